// Round 1
// baseline (286.547 us; speedup 1.0000x reference)
//
#include <hip/hip_runtime.h>
#include <math.h>

#define B_ 64
#define N_ 512
#define P_ 256
#define E_ 4096
#define F_ 32
#define H_ 64
#define W_ 8
#define G_ 64
#define RH_ 256

// ---- workspace layout (float offsets) ----
#define X_OFF   0
#define T4_OFF  (X_OFF + N_*B_*F_)       // x:  [n][b][f]   1,048,576
#define T3_OFF  (T4_OFF + N_*B_*H_)      // t4: [n][b][h]   2,097,152 (includes t2)
#define KB_OFF  (T3_OFF + P_*B_*H_)      // t3: [p][b][h]   1,048,576
#define KW_OFF  (KB_OFF + E_*H_)         // kb: [e][h]        262,144
#define YG_OFF  (KW_OFF + E_*B_*W_)      // kw: [e][b][w]   2,097,152
#define HB_OFF  (YG_OFF + B_*P_*G_)      // yg: [b][p*64+g] 1,048,576
#define RES_OFF (HB_OFF + B_*RH_)        // hbuf: [b][rh]      16,384
#define INT_OFF (RES_OFF + B_*G_)        // res: [b][g]         4,096
// int region at INT_OFF: lidx[4096] | ridx[4096] | part_start[512] | part_edges[4096]

// ---------------------------------------------------------------------------
// Decode one-hot linc (P,E) -> lidx[e], rinc (E,N) -> ridx[e]
__global__ __launch_bounds__(256) void k_decode(const float* __restrict__ linc,
    const float* __restrict__ rinc, int* __restrict__ lidx, int* __restrict__ ridx) {
  int i4 = blockIdx.x * 256 + threadIdx.x;
  const int L4 = (P_ * E_) / 4;  // 262144
  if (i4 < L4) {
    float4 v = ((const float4*)linc)[i4];
    int i = i4 * 4;
    int p = i >> 12, e = i & 4095;
    if (v.x != 0.0f) lidx[e]     = p;
    if (v.y != 0.0f) lidx[e + 1] = p;
    if (v.z != 0.0f) lidx[e + 2] = p;
    if (v.w != 0.0f) lidx[e + 3] = p;
  } else {
    int j4 = i4 - L4;
    float4 v = ((const float4*)rinc)[j4];
    int j = j4 * 4;
    int e = j >> 9, n = j & 511;
    if (v.x != 0.0f) ridx[e] = n;
    if (v.y != 0.0f) ridx[e] = n + 1;
    if (v.z != 0.0f) ridx[e] = n + 2;
    if (v.w != 0.0f) ridx[e] = n + 3;
  }
}

// Counting-sort edges by partition. Single block of 256.
__global__ __launch_bounds__(256) void k_lists(const int* __restrict__ lidx,
    int* __restrict__ part_start, int* __restrict__ part_edges) {
  __shared__ int cnt[256];
  __shared__ int buf[256];
  __shared__ int cur[256];
  int t = threadIdx.x;
  cnt[t] = 0;
  __syncthreads();
  for (int e = t; e < E_; e += 256) atomicAdd(&cnt[lidx[e]], 1);
  __syncthreads();
  int v = cnt[t];
  buf[t] = v;
  __syncthreads();
  for (int off = 1; off < 256; off <<= 1) {
    int add = (t >= off) ? buf[t - off] : 0;
    __syncthreads();
    buf[t] += add;
    __syncthreads();
  }
  part_start[t + 1] = buf[t];           // inclusive scan -> start[p+1]
  if (t == 0) part_start[0] = 0;
  cur[t] = buf[t] - v;                  // exclusive
  __syncthreads();
  for (int e = t; e < E_; e += 256) {
    int p = lidx[e];
    int pos = atomicAdd(&cur[p], 1);
    part_edges[pos] = e;
  }
}

// Grouped conv (K=16, VALID, 1 out pos) + bias + relu -> x[n][b][f]
__global__ __launch_bounds__(256) void k_conv(const float* __restrict__ x1,
    const float* __restrict__ conv_w, const float* __restrict__ conv_b,
    float* __restrict__ x) {
  __shared__ float wsm[32 * 132];  // row pad 132 floats (33 float4) -> 4-way max conflict
  __shared__ float xsm[8192];      // [b][128]
  int n = blockIdx.x, t = threadIdx.x;
  for (int i = t; i < 1024; i += 256) {
    int f = i >> 5, j = i & 31;
    ((float4*)wsm)[f * 33 + j] = ((const float4*)(conv_w + n * 4096))[i];
  }
  for (int i = t; i < 2048; i += 256) {
    int b = i >> 5, j = i & 31;
    ((float4*)xsm)[i] = ((const float4*)(x1 + b * 65536 + n * 128))[j];
  }
  __syncthreads();
  int f = t & 31, bq = t >> 5;
  float cb = conv_b[n * 32 + f];
  float acc[8];
#pragma unroll
  for (int bi = 0; bi < 8; bi++) acc[bi] = cb;
  const float4* wf4 = (const float4*)wsm + f * 33;
  const float4* xb4 = (const float4*)xsm + bq * 256;
#pragma unroll 4
  for (int k4 = 0; k4 < 32; k4++) {
    float4 wv = wf4[k4];
#pragma unroll
    for (int bi = 0; bi < 8; bi++) {
      float4 xv = xb4[bi * 32 + k4];
      acc[bi] += wv.x * xv.x + wv.y * xv.y + wv.z * xv.z + wv.w * xv.w;
    }
  }
#pragma unroll
  for (int bi = 0; bi < 8; bi++) {
    int b = bq * 8 + bi;
    x[n * 2048 + b * 32 + f] = fmaxf(acc[bi], 0.0f);
  }
}

// blocks [0,512): t4[n][b][h] = x[n]@k4_w^T + x2@k2_w^T   (t2 folded in)
// blocks [512,768): t3[p][b][h] = x[pidx[p]]@k3_w^T
// blocks [768,1792): kb[e][h] = ef[e,:8]@k1_w^T + k1_b
// blocks [1792,1856): hbuf[b][rh] = x2@r1_w^T + r1_b + cap@r2_w^T
__global__ __launch_bounds__(256) void k_prep(
    const float* __restrict__ x, const int* __restrict__ pidx,
    const float* __restrict__ k3_w, const float* __restrict__ k4_w,
    const float* __restrict__ x2, const float* __restrict__ k2_w,
    const float* __restrict__ ef, const float* __restrict__ k1_w,
    const float* __restrict__ k1_b,
    const float* __restrict__ r1_w, const float* __restrict__ r1_b,
    const float* __restrict__ r2_w, const float* __restrict__ cap,
    float* __restrict__ t4, float* __restrict__ t3, float* __restrict__ kb,
    float* __restrict__ hbuf) {
  __shared__ float xsh[2048];
  __shared__ float wsh[64 * 36];
  __shared__ float x2s[512];
  __shared__ float k2s[512];
  int blk = blockIdx.x, t = threadIdx.x;
  if (blk < 768) {
    bool isT4 = blk < 512;
    int n = isT4 ? blk : pidx[blk - 512];
    const float* wmat = isT4 ? k4_w : k3_w;
    float* outp = isT4 ? (t4 + blk * 4096) : (t3 + (blk - 512) * 4096);
    for (int i = t; i < 512; i += 256) {
      ((float4*)xsh)[i] = ((const float4*)(x + n * 2048))[i];
      int h = i >> 3, j = i & 7;
      ((float4*)wsh)[h * 9 + j] = ((const float4*)wmat)[i];
    }
    if (isT4) {
      for (int i = t; i < 128; i += 256) {
        ((float4*)x2s)[i] = ((const float4*)x2)[i];
        ((float4*)k2s)[i] = ((const float4*)k2_w)[i];
      }
    }
    __syncthreads();
    int h = t & 63, bq = t >> 6;
    float wreg[32];
#pragma unroll
    for (int j = 0; j < 8; j++) {
      float4 v = ((float4*)wsh)[h * 9 + j];
      wreg[4 * j] = v.x; wreg[4 * j + 1] = v.y; wreg[4 * j + 2] = v.z; wreg[4 * j + 3] = v.w;
    }
    float w2[8];
    if (isT4) {
      float4 u = ((float4*)k2s)[h * 2], v = ((float4*)k2s)[h * 2 + 1];
      w2[0] = u.x; w2[1] = u.y; w2[2] = u.z; w2[3] = u.w;
      w2[4] = v.x; w2[5] = v.y; w2[6] = v.z; w2[7] = v.w;
    }
    for (int bi = 0; bi < 16; bi++) {
      int b = bq * 16 + bi;
      float acc = 0.0f;
#pragma unroll
      for (int j = 0; j < 8; j++) {
        float4 xv = ((float4*)xsh)[b * 8 + j];
        acc += xv.x * wreg[4 * j] + xv.y * wreg[4 * j + 1] +
               xv.z * wreg[4 * j + 2] + xv.w * wreg[4 * j + 3];
      }
      if (isT4) {
        float4 u = ((float4*)x2s)[b * 2], v = ((float4*)x2s)[b * 2 + 1];
        acc += u.x * w2[0] + u.y * w2[1] + u.z * w2[2] + u.w * w2[3] +
               v.x * w2[4] + v.y * w2[5] + v.z * w2[6] + v.w * w2[7];
      }
      outp[b * 64 + h] = acc;
    }
  } else if (blk < 1792) {
    int o = (blk - 768) * 256 + t;
    int e = o >> 6, h = o & 63;
    float acc = k1_b[h];
    const float* er = ef + e * 9;
    const float* kr = k1_w + h * 8;
#pragma unroll
    for (int d = 0; d < 8; d++) acc += er[d] * kr[d];
    kb[o] = acc;
  } else {
    int o = (blk - 1792) * 256 + t;
    int rh = o & 255;
    float acc = r1_b[rh];
    const float* xr = x2 + (o >> 8) * 8;
    const float* rr = r1_w + rh * 8;
#pragma unroll
    for (int d = 0; d < 8; d++) acc += xr[d] * rr[d];
    const float* r2r = r2_w + rh * 256;
    for (int p4 = 0; p4 < 64; p4++) {
      float4 cv = ((const float4*)cap)[p4];
      float4 rv = ((const float4*)r2r)[p4];
      acc += cv.x * rv.x + cv.y * rv.y + cv.z * rv.z + cv.w * rv.w;
    }
    hbuf[o] = acc;
  }
}

// Per-edge: kern = kb[e]+t3[lidx]+t4[ridx]; leaky(0.02); @k5_w^T + k5_b; relu -> kw[e][b][w]
__global__ __launch_bounds__(256) void k_edge(
    const float* __restrict__ kb, const float* __restrict__ t3,
    const float* __restrict__ t4, const float* __restrict__ k5_w,
    const float* __restrict__ k5_b, const int* __restrict__ lidx,
    const int* __restrict__ ridx, float* __restrict__ kw) {
  __shared__ float k5t[4 * 520];  // k5t[q][h*8+w], q-replicated (bank-offset) copies
  int e = blockIdx.x, t = threadIdx.x;
  for (int i = t; i < 512; i += 256) {
    int h = i >> 3, w = i & 7;
    float v = k5_w[w * 64 + h];
#pragma unroll
    for (int qq = 0; qq < 4; qq++) k5t[qq * 520 + i] = v;
  }
  int p = lidx[e], r = ridx[e];
  int q = t & 3, b = t >> 2;
  const float4* kb4 = (const float4*)(kb + e * 64 + q * 16);
  const float4* t34 = (const float4*)(t3 + p * 4096 + b * 64 + q * 16);
  const float4* t44 = (const float4*)(t4 + r * 4096 + b * 64 + q * 16);
  __syncthreads();
  float lk[16];
#pragma unroll
  for (int j4 = 0; j4 < 4; j4++) {
    float4 a = kb4[j4], c = t34[j4], d = t44[j4];
    float v;
    v = a.x + c.x + d.x; lk[j4 * 4 + 0] = v > 0.0f ? v : 0.02f * v;
    v = a.y + c.y + d.y; lk[j4 * 4 + 1] = v > 0.0f ? v : 0.02f * v;
    v = a.z + c.z + d.z; lk[j4 * 4 + 2] = v > 0.0f ? v : 0.02f * v;
    v = a.w + c.w + d.w; lk[j4 * 4 + 3] = v > 0.0f ? v : 0.02f * v;
  }
  float pw[8] = {0, 0, 0, 0, 0, 0, 0, 0};
  const float* kq = k5t + q * 520 + q * 128;  // rows h = q*16..q*16+15
#pragma unroll
  for (int j = 0; j < 16; j++) {
    float4 u = *(const float4*)(kq + j * 8);
    float4 v = *(const float4*)(kq + j * 8 + 4);
    float l = lk[j];
    pw[0] += l * u.x; pw[1] += l * u.y; pw[2] += l * u.z; pw[3] += l * u.w;
    pw[4] += l * v.x; pw[5] += l * v.y; pw[6] += l * v.z; pw[7] += l * v.w;
  }
#pragma unroll
  for (int w = 0; w < 8; w++) {  // reduce over the 4 h-quarter lanes (bits 0..1)
    pw[w] += __shfl_xor(pw[w], 1);
    pw[w] += __shfl_xor(pw[w], 2);
  }
  float2 o;
  o.x = fmaxf(pw[2 * q] + k5_b[2 * q], 0.0f);
  o.y = fmaxf(pw[2 * q + 1] + k5_b[2 * q + 1], 0.0f);
  *(float2*)(kw + e * 512 + t * 2) = o;  // kw[e][b][2q..2q+1], fully coalesced
}

// Per-partition: agg[b][wf] (registers) = sum_e kw[e][b][w]*x[ridx[e]][b][f];
// then yg[b][p*64+g] = relu(agg . gc_w[g] + gc_b[g])  (gc_w staged in LDS, 2 halves)
__global__ __launch_bounds__(256) void k_agg_gc(const float* __restrict__ x,
    const float* __restrict__ kw, const int* __restrict__ ridx,
    const int* __restrict__ part_start, const int* __restrict__ part_edges,
    const float* __restrict__ gc_w, const float* __restrict__ gc_b,
    float* __restrict__ yg) {
  __shared__ float gws[8192];  // 32 rows x 256
  int p = blockIdx.x, t = threadIdx.x;
  int q = t & 3, b = t >> 2;
  float acc[8][8];  // acc[w][j] for wf = w*32 + q*8 + j
#pragma unroll
  for (int w = 0; w < 8; w++)
#pragma unroll
    for (int j = 0; j < 8; j++) acc[w][j] = 0.0f;
  int s0 = part_start[p], s1 = part_start[p + 1];
  for (int idx = s0; idx < s1; idx++) {
    int e = part_edges[idx];
    int r = ridx[e];
    const float* kwp = kw + e * 512 + b * 8;
    float4 ka = *(const float4*)kwp;
    float4 kb2 = *(const float4*)(kwp + 4);
    const float* rxp = x + r * 2048 + b * 32 + q * 8;
    float4 ra = *(const float4*)rxp;
    float4 rb = *(const float4*)(rxp + 4);
    float kv[8] = {ka.x, ka.y, ka.z, ka.w, kb2.x, kb2.y, kb2.z, kb2.w};
    float rv[8] = {ra.x, ra.y, ra.z, ra.w, rb.x, rb.y, rb.z, rb.w};
#pragma unroll
    for (int w = 0; w < 8; w++)
#pragma unroll
      for (int j = 0; j < 8; j++) acc[w][j] += kv[w] * rv[j];
  }
  for (int half = 0; half < 2; half++) {
    __syncthreads();
    for (int i = t; i < 2048; i += 256)
      ((float4*)gws)[i] = ((const float4*)gc_w)[half * 2048 + i];
    __syncthreads();
    for (int gi = 0; gi < 32; gi++) {
      int g = half * 32 + gi;
      const float* gr = gws + gi * 256 + q * 8;
      float part = 0.0f;
#pragma unroll
      for (int w = 0; w < 8; w++) {
        float4 u = *(const float4*)(gr + w * 32);
        float4 v = *(const float4*)(gr + w * 32 + 4);
        part += acc[w][0] * u.x + acc[w][1] * u.y + acc[w][2] * u.z + acc[w][3] * u.w +
                acc[w][4] * v.x + acc[w][5] * v.y + acc[w][6] * v.z + acc[w][7] * v.w;
      }
      part += __shfl_xor(part, 1);
      part += __shfl_xor(part, 2);
      if (q == (g & 3))
        yg[b * 16384 + p * 64 + g] = fmaxf(part + gc_b[g], 0.0f);
    }
  }
}

// Split-K GEMM: hbuf[b][rh] += yg[b,:] . r0_w[rh,:]   (grid = 8 rh-tiles x 32 k-chunks)
__global__ __launch_bounds__(256) void k_r0(const float* __restrict__ yg,
    const float* __restrict__ r0_w, float* __restrict__ hbuf) {
  __shared__ float ygs[64 * 68];  // [b][64k], row pad 68
  __shared__ float r0s[32 * 68];
  int blk = blockIdx.x;
  int rt = blk >> 5, kc = blk & 31;
  int t = threadIdx.x;
  int bg = t & 15, rg = t >> 4;
  float acc[4][2];
#pragma unroll
  for (int bi = 0; bi < 4; bi++)
#pragma unroll
    for (int ri = 0; ri < 2; ri++) acc[bi][ri] = 0.0f;
  for (int ks = 0; ks < 8; ks++) {
    int kbase = kc * 512 + ks * 64;
    __syncthreads();
    for (int i = t; i < 1024; i += 256) {
      int b = i >> 4, j = i & 15;
      ((float4*)ygs)[b * 17 + j] = *((const float4*)(yg + b * 16384 + kbase) + j);
    }
    for (int i = t; i < 512; i += 256) {
      int r = i >> 4, j = i & 15;
      ((float4*)r0s)[r * 17 + j] = *((const float4*)(r0_w + (rt * 32 + r) * 16384 + kbase) + j);
    }
    __syncthreads();
#pragma unroll 4
    for (int k4 = 0; k4 < 16; k4++) {
      float4 yv[4], rv[2];
#pragma unroll
      for (int bi = 0; bi < 4; bi++) yv[bi] = ((float4*)ygs)[(bg * 4 + bi) * 17 + k4];
#pragma unroll
      for (int ri = 0; ri < 2; ri++) rv[ri] = ((float4*)r0s)[(rg * 2 + ri) * 17 + k4];
#pragma unroll
      for (int bi = 0; bi < 4; bi++)
#pragma unroll
        for (int ri = 0; ri < 2; ri++)
          acc[bi][ri] += yv[bi].x * rv[ri].x + yv[bi].y * rv[ri].y +
                         yv[bi].z * rv[ri].z + yv[bi].w * rv[ri].w;
    }
  }
#pragma unroll
  for (int bi = 0; bi < 4; bi++)
#pragma unroll
    for (int ri = 0; ri < 2; ri++)
      atomicAdd(&hbuf[(bg * 4 + bi) * 256 + rt * 32 + rg * 2 + ri], acc[bi][ri]);
}

// Per-b: wt[p] = relu(leaky(h,0.01) . r3_w[p] + r3_b[p]); res[g] = sum_p wt[p]*yg[b,p,g]
__global__ __launch_bounds__(256) void k_wt_res(const float* __restrict__ hbuf,
    const float* __restrict__ r3_w, const float* __restrict__ r3_b,
    const float* __restrict__ yg, float* __restrict__ res) {
  __shared__ float hs[256];
  __shared__ float wts[256];
  __shared__ float red[256];
  int bb = blockIdx.x, t = threadIdx.x;
  float hv = hbuf[bb * 256 + t];
  hs[t] = hv > 0.0f ? hv : 0.01f * hv;
  __syncthreads();
  float acc = r3_b[t];
  const float4* wrow = (const float4*)(r3_w + t * 256);
#pragma unroll 8
  for (int j = 0; j < 64; j++) {
    float4 h4 = ((float4*)hs)[j];
    float4 w4 = wrow[j];
    acc += h4.x * w4.x + h4.y * w4.y + h4.z * w4.z + h4.w * w4.w;
  }
  wts[t] = fmaxf(acc, 0.0f);
  __syncthreads();
  int g = t & 63, pq = t >> 6;
  float r = 0.0f;
  for (int pi = 0; pi < 64; pi++) {
    int p = pq * 64 + pi;
    r += wts[p] * yg[bb * 16384 + p * 64 + g];
  }
  red[t] = r;
  __syncthreads();
  if (t < 64) res[bb * 64 + t] = red[t] + red[t + 64] + red[t + 128] + red[t + 192];
}

// z = elu([res, x2] @ l1_w^T + l1_b); out = z @ l3_w^T + l3_b
__global__ __launch_bounds__(128) void k_final(const float* __restrict__ res,
    const float* __restrict__ x2, const float* __restrict__ l1_w,
    const float* __restrict__ l1_b, const float* __restrict__ l3_w,
    const float* __restrict__ l3_b, float* __restrict__ out) {
  __shared__ float zs[128];
  int bb = blockIdx.x, t = threadIdx.x;
  float acc = l1_b[t];
  const float* wrow = l1_w + t * 72;
  const float* rr = res + bb * 64;
#pragma unroll 8
  for (int j = 0; j < 64; j++) acc += rr[j] * wrow[j];
  const float* xr = x2 + bb * 8;
#pragma unroll
  for (int j = 0; j < 8; j++) acc += xr[j] * wrow[64 + j];
  zs[t] = acc > 0.0f ? acc : expm1f(acc);
  __syncthreads();
  if (t < 9) {
    float o = l3_b[t];
    const float* w3 = l3_w + t * 128;
    for (int j = 0; j < 128; j++) o += zs[j] * w3[j];
    out[bb * 9 + t] = o;
  }
}

extern "C" void kernel_launch(void* const* d_in, const int* in_sizes, int n_in,
                              void* d_out, int out_size, void* d_ws, size_t ws_size,
                              hipStream_t stream) {
  (void)in_sizes; (void)n_in; (void)out_size; (void)ws_size;
  const float* x1     = (const float*)d_in[0];
  const float* x2     = (const float*)d_in[1];
  const float* conv_w = (const float*)d_in[2];
  const float* conv_b = (const float*)d_in[3];
  const float* k1_w   = (const float*)d_in[4];
  const float* k1_b   = (const float*)d_in[5];
  const float* k2_w   = (const float*)d_in[6];
  const float* k3_w   = (const float*)d_in[7];
  const float* k4_w   = (const float*)d_in[8];
  const float* k5_w   = (const float*)d_in[9];
  const float* k5_b   = (const float*)d_in[10];
  const float* gc_w   = (const float*)d_in[11];
  const float* gc_b   = (const float*)d_in[12];
  const float* r0_w   = (const float*)d_in[13];
  const float* r1_w   = (const float*)d_in[14];
  const float* r1_b   = (const float*)d_in[15];
  const float* r2_w   = (const float*)d_in[16];
  const float* r3_w   = (const float*)d_in[17];
  const float* r3_b   = (const float*)d_in[18];
  const float* l1_w   = (const float*)d_in[19];
  const float* l1_b   = (const float*)d_in[20];
  const float* l3_w   = (const float*)d_in[21];
  const float* l3_b   = (const float*)d_in[22];
  const float* ef     = (const float*)d_in[23];
  const float* linc   = (const float*)d_in[24];
  const float* rinc   = (const float*)d_in[25];
  const float* cap    = (const float*)d_in[26];
  const int*   pidx   = (const int*)d_in[27];
  float* out = (float*)d_out;

  float* ws   = (float*)d_ws;
  float* xbuf = ws + X_OFF;
  float* t4   = ws + T4_OFF;
  float* t3   = ws + T3_OFF;
  float* kb   = ws + KB_OFF;
  float* kw   = ws + KW_OFF;
  float* yg   = ws + YG_OFF;
  float* hbuf = ws + HB_OFF;
  float* res  = ws + RES_OFF;
  int* ib = (int*)(ws + INT_OFF);
  int* lidx = ib;
  int* ridx = ib + 4096;
  int* part_start = ib + 8192;   // 257 used
  int* part_edges = ib + 8704;

  hipLaunchKernelGGL(k_decode, dim3(3072), dim3(256), 0, stream, linc, rinc, lidx, ridx);
  hipLaunchKernelGGL(k_lists, dim3(1), dim3(256), 0, stream, lidx, part_start, part_edges);
  hipLaunchKernelGGL(k_conv, dim3(512), dim3(256), 0, stream, x1, conv_w, conv_b, xbuf);
  hipLaunchKernelGGL(k_prep, dim3(1856), dim3(256), 0, stream,
                     xbuf, pidx, k3_w, k4_w, x2, k2_w, ef, k1_w, k1_b,
                     r1_w, r1_b, r2_w, cap, t4, t3, kb, hbuf);
  hipLaunchKernelGGL(k_edge, dim3(4096), dim3(256), 0, stream,
                     kb, t3, t4, k5_w, k5_b, lidx, ridx, kw);
  hipLaunchKernelGGL(k_agg_gc, dim3(256), dim3(256), 0, stream,
                     xbuf, kw, ridx, part_start, part_edges, gc_w, gc_b, yg);
  hipLaunchKernelGGL(k_r0, dim3(256), dim3(256), 0, stream, yg, r0_w, hbuf);
  hipLaunchKernelGGL(k_wt_res, dim3(64), dim3(256), 0, stream, hbuf, r3_w, r3_b, yg, res);
  hipLaunchKernelGGL(k_final, dim3(64), dim3(128), 0, stream,
                     res, x2, l1_w, l1_b, l3_w, l3_b, out);
}

// Round 2
// 273.215 us; speedup vs baseline: 1.0488x; 1.0488x over previous
//
#include <hip/hip_runtime.h>
#include <math.h>

#define B_ 64
#define N_ 512
#define P_ 256
#define E_ 4096
#define F_ 32
#define H_ 64
#define W_ 8
#define G_ 64
#define RH_ 256

// ---- workspace layout (float offsets) ----
#define X_OFF   0
#define T4_OFF  (X_OFF + N_*B_*F_)       // x:  [n][b][f]
#define T3_OFF  (T4_OFF + N_*B_*H_)      // t4: [n][b][h] (t2 folded in)
#define KB_OFF  (T3_OFF + P_*B_*H_)      // t3: [p][b][h]
#define KW_OFF  (KB_OFF + E_*H_)         // kb: [e][h]
#define YG_OFF  (KW_OFF + E_*B_*W_)      // kw: [e][b][w]
#define HB_OFF  (YG_OFF + B_*P_*G_)      // yg: [b][p*64+g]
#define RES_OFF (HB_OFF + B_*RH_)        // hbuf: [b][rh]
#define INT_OFF (RES_OFF + 4*B_*G_)      // res4: [pq][b][g]  (4 partials)
// int region at INT_OFF: lidx[4096] | ridx[4096] | part_start[512] | part_edges[4096]

// ---------------------------------------------------------------------------
__global__ __launch_bounds__(256) void k_decode(const float* __restrict__ linc,
    const float* __restrict__ rinc, int* __restrict__ lidx, int* __restrict__ ridx) {
  int i4 = blockIdx.x * 256 + threadIdx.x;
  const int L4 = (P_ * E_) / 4;  // 262144
  if (i4 < L4) {
    float4 v = ((const float4*)linc)[i4];
    int i = i4 * 4;
    int p = i >> 12, e = i & 4095;
    if (v.x != 0.0f) lidx[e]     = p;
    if (v.y != 0.0f) lidx[e + 1] = p;
    if (v.z != 0.0f) lidx[e + 2] = p;
    if (v.w != 0.0f) lidx[e + 3] = p;
  } else {
    int j4 = i4 - L4;
    float4 v = ((const float4*)rinc)[j4];
    int j = j4 * 4;
    int e = j >> 9, n = j & 511;
    if (v.x != 0.0f) ridx[e] = n;
    if (v.y != 0.0f) ridx[e] = n + 1;
    if (v.z != 0.0f) ridx[e] = n + 2;
    if (v.w != 0.0f) ridx[e] = n + 3;
  }
}

// Counting-sort edges by partition. Single block of 1024.
__global__ __launch_bounds__(1024) void k_lists(const int* __restrict__ lidx,
    int* __restrict__ part_start, int* __restrict__ part_edges) {
  __shared__ int cnt[256];
  __shared__ int buf[256];
  __shared__ int cur[256];
  int t = threadIdx.x;
  if (t < 256) cnt[t] = 0;
  __syncthreads();
  for (int e = t; e < E_; e += 1024) atomicAdd(&cnt[lidx[e]], 1);
  __syncthreads();
  if (t < 256) buf[t] = cnt[t];
  __syncthreads();
  for (int off = 1; off < 256; off <<= 1) {
    int add = 0;
    if (t < 256 && t >= off) add = buf[t - off];
    __syncthreads();
    if (t < 256) buf[t] += add;
    __syncthreads();
  }
  if (t < 256) {
    part_start[t + 1] = buf[t];
    if (t == 0) part_start[0] = 0;
    cur[t] = buf[t] - cnt[t];
  }
  __syncthreads();
  for (int e = t; e < E_; e += 1024) {
    int p = lidx[e];
    int pos = atomicAdd(&cur[p], 1);
    part_edges[pos] = e;
  }
}

// Grouped conv (K=16, VALID, 1 out pos) + bias + relu -> x[n][b][f]
__global__ __launch_bounds__(256) void k_conv(const float* __restrict__ x1,
    const float* __restrict__ conv_w, const float* __restrict__ conv_b,
    float* __restrict__ x) {
  __shared__ float wsm[32 * 132];
  __shared__ float xsm[8192];
  int n = blockIdx.x, t = threadIdx.x;
  for (int i = t; i < 1024; i += 256) {
    int f = i >> 5, j = i & 31;
    ((float4*)wsm)[f * 33 + j] = ((const float4*)(conv_w + n * 4096))[i];
  }
  for (int i = t; i < 2048; i += 256) {
    int b = i >> 5, j = i & 31;
    ((float4*)xsm)[i] = ((const float4*)(x1 + b * 65536 + n * 128))[j];
  }
  __syncthreads();
  int f = t & 31, bq = t >> 5;
  float cb = conv_b[n * 32 + f];
  float acc[8];
#pragma unroll
  for (int bi = 0; bi < 8; bi++) acc[bi] = cb;
  const float4* wf4 = (const float4*)wsm + f * 33;
  const float4* xb4 = (const float4*)xsm + bq * 256;
#pragma unroll 4
  for (int k4 = 0; k4 < 32; k4++) {
    float4 wv = wf4[k4];
#pragma unroll
    for (int bi = 0; bi < 8; bi++) {
      float4 xv = xb4[bi * 32 + k4];
      acc[bi] += wv.x * xv.x + wv.y * xv.y + wv.z * xv.z + wv.w * xv.w;
    }
  }
#pragma unroll
  for (int bi = 0; bi < 8; bi++) {
    int b = bq * 8 + bi;
    x[n * 2048 + b * 32 + f] = fmaxf(acc[bi], 0.0f);
  }
}

// blocks [0,512): t4[n][b][h] = x[n]@k4_w^T + x2@k2_w^T
// blocks [512,768): t3[p][b][h] = x[pidx[p]]@k3_w^T
// blocks [768,1792): kb[e][h] = ef[e,:8]@k1_w^T + k1_b
// blocks [1792,1856): hbuf[b][rh] = x2@r1_w^T + r1_b + cap@r2_w^T
__global__ __launch_bounds__(256) void k_prep(
    const float* __restrict__ x, const int* __restrict__ pidx,
    const float* __restrict__ k3_w, const float* __restrict__ k4_w,
    const float* __restrict__ x2, const float* __restrict__ k2_w,
    const float* __restrict__ ef, const float* __restrict__ k1_w,
    const float* __restrict__ k1_b,
    const float* __restrict__ r1_w, const float* __restrict__ r1_b,
    const float* __restrict__ r2_w, const float* __restrict__ cap,
    float* __restrict__ t4, float* __restrict__ t3, float* __restrict__ kb,
    float* __restrict__ hbuf) {
  __shared__ float xsh[2048];
  __shared__ float wsh[64 * 36];
  __shared__ float x2s[512];
  __shared__ float k2s[512];
  int blk = blockIdx.x, t = threadIdx.x;
  if (blk < 768) {
    bool isT4 = blk < 512;
    int n = isT4 ? blk : pidx[blk - 512];
    const float* wmat = isT4 ? k4_w : k3_w;
    float* outp = isT4 ? (t4 + blk * 4096) : (t3 + (blk - 512) * 4096);
    for (int i = t; i < 512; i += 256) {
      ((float4*)xsh)[i] = ((const float4*)(x + n * 2048))[i];
      int h = i >> 3, j = i & 7;
      ((float4*)wsh)[h * 9 + j] = ((const float4*)wmat)[i];
    }
    if (isT4) {
      for (int i = t; i < 128; i += 256) {
        ((float4*)x2s)[i] = ((const float4*)x2)[i];
        ((float4*)k2s)[i] = ((const float4*)k2_w)[i];
      }
    }
    __syncthreads();
    int h = t & 63, bq = t >> 6;
    float wreg[32];
#pragma unroll
    for (int j = 0; j < 8; j++) {
      float4 v = ((float4*)wsh)[h * 9 + j];
      wreg[4 * j] = v.x; wreg[4 * j + 1] = v.y; wreg[4 * j + 2] = v.z; wreg[4 * j + 3] = v.w;
    }
    float w2[8];
    if (isT4) {
      float4 u = ((float4*)k2s)[h * 2], v = ((float4*)k2s)[h * 2 + 1];
      w2[0] = u.x; w2[1] = u.y; w2[2] = u.z; w2[3] = u.w;
      w2[4] = v.x; w2[5] = v.y; w2[6] = v.z; w2[7] = v.w;
    }
    for (int bi = 0; bi < 16; bi++) {
      int b = bq * 16 + bi;
      float acc = 0.0f;
#pragma unroll
      for (int j = 0; j < 8; j++) {
        float4 xv = ((float4*)xsh)[b * 8 + j];
        acc += xv.x * wreg[4 * j] + xv.y * wreg[4 * j + 1] +
               xv.z * wreg[4 * j + 2] + xv.w * wreg[4 * j + 3];
      }
      if (isT4) {
        float4 u = ((float4*)x2s)[b * 2], v = ((float4*)x2s)[b * 2 + 1];
        acc += u.x * w2[0] + u.y * w2[1] + u.z * w2[2] + u.w * w2[3] +
               v.x * w2[4] + v.y * w2[5] + v.z * w2[6] + v.w * w2[7];
      }
      outp[b * 64 + h] = acc;
    }
  } else if (blk < 1792) {
    int o = (blk - 768) * 256 + t;
    int e = o >> 6, h = o & 63;
    float acc = k1_b[h];
    const float* er = ef + e * 9;
    const float* kr = k1_w + h * 8;
#pragma unroll
    for (int d = 0; d < 8; d++) acc += er[d] * kr[d];
    kb[o] = acc;
  } else {
    int o = (blk - 1792) * 256 + t;
    int rh = o & 255;
    float acc = r1_b[rh];
    const float* xr = x2 + (o >> 8) * 8;
    const float* rr = r1_w + rh * 8;
#pragma unroll
    for (int d = 0; d < 8; d++) acc += xr[d] * rr[d];
    const float* r2r = r2_w + rh * 256;
    for (int p4 = 0; p4 < 64; p4++) {
      float4 cv = ((const float4*)cap)[p4];
      float4 rv = ((const float4*)r2r)[p4];
      acc += cv.x * rv.x + cv.y * rv.y + cv.z * rv.z + cv.w * rv.w;
    }
    hbuf[o] = acc;
  }
}

// Per-edge: kern = kb[e]+t3[lidx]+t4[ridx]; leaky(0.02); @k5_w^T + k5_b; relu -> kw[e][b][w]
__global__ __launch_bounds__(256) void k_edge(
    const float* __restrict__ kb, const float* __restrict__ t3,
    const float* __restrict__ t4, const float* __restrict__ k5_w,
    const float* __restrict__ k5_b, const int* __restrict__ lidx,
    const int* __restrict__ ridx, float* __restrict__ kw) {
  __shared__ float k5t[4 * 520];
  int e = blockIdx.x, t = threadIdx.x;
  for (int i = t; i < 512; i += 256) {
    int h = i >> 3, w = i & 7;
    float v = k5_w[w * 64 + h];
#pragma unroll
    for (int qq = 0; qq < 4; qq++) k5t[qq * 520 + i] = v;
  }
  int p = lidx[e], r = ridx[e];
  int q = t & 3, b = t >> 2;
  const float4* kb4 = (const float4*)(kb + e * 64 + q * 16);
  const float4* t34 = (const float4*)(t3 + p * 4096 + b * 64 + q * 16);
  const float4* t44 = (const float4*)(t4 + r * 4096 + b * 64 + q * 16);
  __syncthreads();
  float lk[16];
#pragma unroll
  for (int j4 = 0; j4 < 4; j4++) {
    float4 a = kb4[j4], c = t34[j4], d = t44[j4];
    float v;
    v = a.x + c.x + d.x; lk[j4 * 4 + 0] = v > 0.0f ? v : 0.02f * v;
    v = a.y + c.y + d.y; lk[j4 * 4 + 1] = v > 0.0f ? v : 0.02f * v;
    v = a.z + c.z + d.z; lk[j4 * 4 + 2] = v > 0.0f ? v : 0.02f * v;
    v = a.w + c.w + d.w; lk[j4 * 4 + 3] = v > 0.0f ? v : 0.02f * v;
  }
  float pw[8] = {0, 0, 0, 0, 0, 0, 0, 0};
  const float* kq = k5t + q * 520 + q * 128;
#pragma unroll
  for (int j = 0; j < 16; j++) {
    float4 u = *(const float4*)(kq + j * 8);
    float4 v = *(const float4*)(kq + j * 8 + 4);
    float l = lk[j];
    pw[0] += l * u.x; pw[1] += l * u.y; pw[2] += l * u.z; pw[3] += l * u.w;
    pw[4] += l * v.x; pw[5] += l * v.y; pw[6] += l * v.z; pw[7] += l * v.w;
  }
#pragma unroll
  for (int w = 0; w < 8; w++) {
    pw[w] += __shfl_xor(pw[w], 1);
    pw[w] += __shfl_xor(pw[w], 2);
  }
  float2 o;
  o.x = fmaxf(pw[2 * q] + k5_b[2 * q], 0.0f);
  o.y = fmaxf(pw[2 * q + 1] + k5_b[2 * q + 1], 0.0f);
  *(float2*)(kw + e * 512 + t * 2) = o;
}

// Per-partition p: acc[b][k] (regs) = sum_e kw[e,b,w]*x[ridx[e],b,f]  (k = w*32+f);
// -> LDS bf16 accS[b][k] (oct-swizzled), then 4 g-split waves compute
// yg[b][p*64+g] = relu(accS[b,:] . gc_w[g,:] + gc_b[g]) with 8b x 2g register tiles.
__global__ __launch_bounds__(256) void k_agg_gc(const float* __restrict__ x,
    const float* __restrict__ kw, const int* __restrict__ ridx,
    const int* __restrict__ part_start, const int* __restrict__ part_edges,
    const float* __restrict__ gc_w, const float* __restrict__ gc_b,
    float* __restrict__ yg) {
  __shared__ unsigned short accS[64 * 256];  // bf16 [b][k], oct' = oct ^ (b>>3)
  int p = blockIdx.x, t = threadIdx.x;
  int b = t >> 2, s = t & 3;   // b in [0,64), s selects k-range [s*64, s*64+64)
  float acc[64];
#pragma unroll
  for (int j = 0; j < 64; j++) acc[j] = 0.0f;
  int s0 = part_start[p], s1 = part_start[p + 1];
  int idx = s0;
  for (; idx + 1 < s1; idx += 2) {
    int e0 = part_edges[idx], e1 = part_edges[idx + 1];
    int r0 = ridx[e0], r1 = ridx[e1];
    float2 ka = *(const float2*)(kw + e0 * 512 + b * 8 + s * 2);
    float2 kc = *(const float2*)(kw + e1 * 512 + b * 8 + s * 2);
    const float4* xp0 = (const float4*)(x + r0 * 2048 + b * 32);
    const float4* xp1 = (const float4*)(x + r1 * 2048 + b * 32);
    float xa[32], xb[32];
#pragma unroll
    for (int i = 0; i < 8; i++) {
      float4 v = xp0[i];
      xa[4 * i] = v.x; xa[4 * i + 1] = v.y; xa[4 * i + 2] = v.z; xa[4 * i + 3] = v.w;
    }
#pragma unroll
    for (int i = 0; i < 8; i++) {
      float4 v = xp1[i];
      xb[4 * i] = v.x; xb[4 * i + 1] = v.y; xb[4 * i + 2] = v.z; xb[4 * i + 3] = v.w;
    }
#pragma unroll
    for (int j = 0; j < 32; j++) acc[j] += ka.x * xa[j];
#pragma unroll
    for (int j = 0; j < 32; j++) acc[32 + j] += ka.y * xa[j];
#pragma unroll
    for (int j = 0; j < 32; j++) acc[j] += kc.x * xb[j];
#pragma unroll
    for (int j = 0; j < 32; j++) acc[32 + j] += kc.y * xb[j];
  }
  if (idx < s1) {
    int e0 = part_edges[idx];
    int r0 = ridx[e0];
    float2 ka = *(const float2*)(kw + e0 * 512 + b * 8 + s * 2);
    const float4* xp0 = (const float4*)(x + r0 * 2048 + b * 32);
    float xa[32];
#pragma unroll
    for (int i = 0; i < 8; i++) {
      float4 v = xp0[i];
      xa[4 * i] = v.x; xa[4 * i + 1] = v.y; xa[4 * i + 2] = v.z; xa[4 * i + 3] = v.w;
    }
#pragma unroll
    for (int j = 0; j < 32; j++) acc[j] += ka.x * xa[j];
#pragma unroll
    for (int j = 0; j < 32; j++) acc[32 + j] += ka.y * xa[j];
  }
  // store acc -> accS (bf16, RNE, oct-swizzled)
#pragma unroll
  for (int o = 0; o < 8; o++) {
    int koct = s * 8 + o;
    int os = koct ^ (b >> 3);
    unsigned int wds[4];
#pragma unroll
    for (int h = 0; h < 4; h++) {
      unsigned int u0 = __float_as_uint(acc[o * 8 + 2 * h]);
      u0 = u0 + 0x7fffu + ((u0 >> 16) & 1u);
      unsigned int u1 = __float_as_uint(acc[o * 8 + 2 * h + 1]);
      u1 = u1 + 0x7fffu + ((u1 >> 16) & 1u);
      wds[h] = (u0 >> 16) | (u1 & 0xffff0000u);
    }
    int4 pk = make_int4((int)wds[0], (int)wds[1], (int)wds[2], (int)wds[3]);
    *(int4*)(accS + b * 256 + os * 8) = pk;
  }
  __syncthreads();
  // epilogue: wave w handles g in [w*16, w*16+16); lane: bg = lane>>3 (8 rows of 8 b), gg = lane&7 (2 g)
  int lane = t & 63, wv = t >> 6;
  int bg = lane >> 3, gg = lane & 7;
  int g0 = wv * 16 + gg * 2;
  const float* gw0 = gc_w + g0 * 256;
  const float* gw1 = gc_w + (g0 + 1) * 256;
  float ac[8][2];
#pragma unroll
  for (int i = 0; i < 8; i++) { ac[i][0] = 0.0f; ac[i][1] = 0.0f; }
  for (int oct = 0; oct < 32; oct++) {
    int4 a8[8];
#pragma unroll
    for (int i = 0; i < 8; i++) {
      int row = bg * 8 + i;
      int os = oct ^ bg;
      a8[i] = *(const int4*)(accS + row * 256 + os * 8);
    }
    float4 b0a = *(const float4*)(gw0 + oct * 8);
    float4 b0b = *(const float4*)(gw0 + oct * 8 + 4);
    float4 b1a = *(const float4*)(gw1 + oct * 8);
    float4 b1b = *(const float4*)(gw1 + oct * 8 + 4);
    float bv0[8] = {b0a.x, b0a.y, b0a.z, b0a.w, b0b.x, b0b.y, b0b.z, b0b.w};
    float bv1[8] = {b1a.x, b1a.y, b1a.z, b1a.w, b1b.x, b1b.y, b1b.z, b1b.w};
#pragma unroll
    for (int kk = 0; kk < 8; kk++) {
#pragma unroll
      for (int i = 0; i < 8; i++) {
        int w32;
        switch (kk >> 1) {
          case 0: w32 = a8[i].x; break;
          case 1: w32 = a8[i].y; break;
          case 2: w32 = a8[i].z; break;
          default: w32 = a8[i].w; break;
        }
        unsigned int u = (unsigned int)w32;
        unsigned int bits = (kk & 1) ? (u & 0xffff0000u) : (u << 16);
        float av = __uint_as_float(bits);
        ac[i][0] += av * bv0[kk];
        ac[i][1] += av * bv1[kk];
      }
    }
  }
  float gb0 = gc_b[g0], gb1 = gc_b[g0 + 1];
#pragma unroll
  for (int i = 0; i < 8; i++) {
    int bb = bg * 8 + i;
    float* yp = yg + bb * 16384 + p * 64;
    yp[g0]     = fmaxf(ac[i][0] + gb0, 0.0f);
    yp[g0 + 1] = fmaxf(ac[i][1] + gb1, 0.0f);
  }
}

// Split-K GEMM: hbuf[b][rh] += yg[b,:] . r0_w[rh,:]   (grid = 8 rh-tiles x 64 k-chunks)
__global__ __launch_bounds__(256) void k_r0(const float* __restrict__ yg,
    const float* __restrict__ r0_w, float* __restrict__ hbuf) {
  __shared__ float ygs[64 * 68];
  __shared__ float r0s[32 * 68];
  int blk = blockIdx.x;
  int rt = blk >> 6, kc = blk & 63;
  int t = threadIdx.x;
  int bg = t & 15, rg = t >> 4;
  float acc[4][2];
#pragma unroll
  for (int bi = 0; bi < 4; bi++)
#pragma unroll
    for (int ri = 0; ri < 2; ri++) acc[bi][ri] = 0.0f;
  for (int ks = 0; ks < 4; ks++) {
    int kbase = kc * 256 + ks * 64;
    __syncthreads();
    for (int i = t; i < 1024; i += 256) {
      int b = i >> 4, j = i & 15;
      ((float4*)ygs)[b * 17 + j] = *((const float4*)(yg + b * 16384 + kbase) + j);
    }
    for (int i = t; i < 512; i += 256) {
      int r = i >> 4, j = i & 15;
      ((float4*)r0s)[r * 17 + j] = *((const float4*)(r0_w + (rt * 32 + r) * 16384 + kbase) + j);
    }
    __syncthreads();
#pragma unroll 4
    for (int k4 = 0; k4 < 16; k4++) {
      float4 yv[4], rv[2];
#pragma unroll
      for (int bi = 0; bi < 4; bi++) yv[bi] = ((float4*)ygs)[(bg * 4 + bi) * 17 + k4];
#pragma unroll
      for (int ri = 0; ri < 2; ri++) rv[ri] = ((float4*)r0s)[(rg * 2 + ri) * 17 + k4];
#pragma unroll
      for (int bi = 0; bi < 4; bi++)
#pragma unroll
        for (int ri = 0; ri < 2; ri++)
          acc[bi][ri] += yv[bi].x * rv[ri].x + yv[bi].y * rv[ri].y +
                         yv[bi].z * rv[ri].z + yv[bi].w * rv[ri].w;
    }
  }
#pragma unroll
  for (int bi = 0; bi < 4; bi++)
#pragma unroll
    for (int ri = 0; ri < 2; ri++)
      atomicAdd(&hbuf[(bg * 4 + bi) * 256 + rt * 32 + rg * 2 + ri], acc[bi][ri]);
}

// grid 256 = (bb, pq): wt for 64 p's, partial res over those p's -> res4[pq][b][g]
__global__ __launch_bounds__(256) void k_wt_res(const float* __restrict__ hbuf,
    const float* __restrict__ r3_w, const float* __restrict__ r3_b,
    const float* __restrict__ yg, float* __restrict__ res4) {
  __shared__ float hs[256];
  __shared__ float wts[64];
  __shared__ float red[256];
  int blk = blockIdx.x;
  int bb = blk >> 2, pq = blk & 3;
  int t = threadIdx.x;
  float hv = hbuf[bb * 256 + t];
  hs[t] = hv > 0.0f ? hv : 0.01f * hv;
  __syncthreads();
  int pl = t >> 2, c = t & 3;
  int pp = pq * 64 + pl;
  const float4* wrow = (const float4*)(r3_w + pp * 256 + c * 64);
  const float4* h4 = (const float4*)(hs) + c * 16;
  float a = 0.0f;
#pragma unroll
  for (int j = 0; j < 16; j++) {
    float4 w4 = wrow[j], hh = h4[j];
    a += hh.x * w4.x + hh.y * w4.y + hh.z * w4.z + hh.w * w4.w;
  }
  a += __shfl_xor(a, 1);
  a += __shfl_xor(a, 2);
  if (c == 0) wts[pl] = fmaxf(a + r3_b[pp], 0.0f);
  __syncthreads();
  int g = t & 63, ch = t >> 6;
  float r = 0.0f;
  const float* ygp = yg + bb * 16384 + pq * 4096 + g;
#pragma unroll
  for (int pi = 0; pi < 16; pi++) {
    int pl2 = ch * 16 + pi;
    r += wts[pl2] * ygp[pl2 * 64];
  }
  red[t] = r;
  __syncthreads();
  if (t < 64)
    res4[pq * 4096 + bb * 64 + t] = red[t] + red[t + 64] + red[t + 128] + red[t + 192];
}

// z = elu([sum(res4), x2] @ l1_w^T + l1_b); out = z @ l3_w^T + l3_b
__global__ __launch_bounds__(128) void k_final(const float* __restrict__ res4,
    const float* __restrict__ x2, const float* __restrict__ l1_w,
    const float* __restrict__ l1_b, const float* __restrict__ l3_w,
    const float* __restrict__ l3_b, float* __restrict__ out) {
  __shared__ float zs[128];
  int bb = blockIdx.x, t = threadIdx.x;
  float acc = l1_b[t];
  const float* wrow = l1_w + t * 72;
  const float* rr = res4 + bb * 64;
#pragma unroll 8
  for (int j = 0; j < 64; j++) {
    float rv = rr[j] + rr[4096 + j] + rr[8192 + j] + rr[12288 + j];
    acc += rv * wrow[j];
  }
  const float* xr = x2 + bb * 8;
#pragma unroll
  for (int j = 0; j < 8; j++) acc += xr[j] * wrow[64 + j];
  zs[t] = acc > 0.0f ? acc : expm1f(acc);
  __syncthreads();
  if (t < 9) {
    float o = l3_b[t];
    const float* w3 = l3_w + t * 128;
    for (int j = 0; j < 128; j++) o += zs[j] * w3[j];
    out[bb * 9 + t] = o;
  }
}

extern "C" void kernel_launch(void* const* d_in, const int* in_sizes, int n_in,
                              void* d_out, int out_size, void* d_ws, size_t ws_size,
                              hipStream_t stream) {
  (void)in_sizes; (void)n_in; (void)out_size; (void)ws_size;
  const float* x1     = (const float*)d_in[0];
  const float* x2     = (const float*)d_in[1];
  const float* conv_w = (const float*)d_in[2];
  const float* conv_b = (const float*)d_in[3];
  const float* k1_w   = (const float*)d_in[4];
  const float* k1_b   = (const float*)d_in[5];
  const float* k2_w   = (const float*)d_in[6];
  const float* k3_w   = (const float*)d_in[7];
  const float* k4_w   = (const float*)d_in[8];
  const float* k5_w   = (const float*)d_in[9];
  const float* k5_b   = (const float*)d_in[10];
  const float* gc_w   = (const float*)d_in[11];
  const float* gc_b   = (const float*)d_in[12];
  const float* r0_w   = (const float*)d_in[13];
  const float* r1_w   = (const float*)d_in[14];
  const float* r1_b   = (const float*)d_in[15];
  const float* r2_w   = (const float*)d_in[16];
  const float* r3_w   = (const float*)d_in[17];
  const float* r3_b   = (const float*)d_in[18];
  const float* l1_w   = (const float*)d_in[19];
  const float* l1_b   = (const float*)d_in[20];
  const float* l3_w   = (const float*)d_in[21];
  const float* l3_b   = (const float*)d_in[22];
  const float* ef     = (const float*)d_in[23];
  const float* linc   = (const float*)d_in[24];
  const float* rinc   = (const float*)d_in[25];
  const float* cap    = (const float*)d_in[26];
  const int*   pidx   = (const int*)d_in[27];
  float* out = (float*)d_out;

  float* ws   = (float*)d_ws;
  float* xbuf = ws + X_OFF;
  float* t4   = ws + T4_OFF;
  float* t3   = ws + T3_OFF;
  float* kb   = ws + KB_OFF;
  float* kwb  = ws + KW_OFF;
  float* yg   = ws + YG_OFF;
  float* hbuf = ws + HB_OFF;
  float* res4 = ws + RES_OFF;
  int* ib = (int*)(ws + INT_OFF);
  int* lidx = ib;
  int* ridx = ib + 4096;
  int* part_start = ib + 8192;
  int* part_edges = ib + 8704;

  hipLaunchKernelGGL(k_decode, dim3(3072), dim3(256), 0, stream, linc, rinc, lidx, ridx);
  hipLaunchKernelGGL(k_lists, dim3(1), dim3(1024), 0, stream, lidx, part_start, part_edges);
  hipLaunchKernelGGL(k_conv, dim3(512), dim3(256), 0, stream, x1, conv_w, conv_b, xbuf);
  hipLaunchKernelGGL(k_prep, dim3(1856), dim3(256), 0, stream,
                     xbuf, pidx, k3_w, k4_w, x2, k2_w, ef, k1_w, k1_b,
                     r1_w, r1_b, r2_w, cap, t4, t3, kb, hbuf);
  hipLaunchKernelGGL(k_edge, dim3(4096), dim3(256), 0, stream,
                     kb, t3, t4, k5_w, k5_b, lidx, ridx, kwb);
  hipLaunchKernelGGL(k_agg_gc, dim3(256), dim3(256), 0, stream,
                     xbuf, kwb, ridx, part_start, part_edges, gc_w, gc_b, yg);
  hipLaunchKernelGGL(k_r0, dim3(512), dim3(256), 0, stream, yg, r0_w, hbuf);
  hipLaunchKernelGGL(k_wt_res, dim3(256), dim3(256), 0, stream, hbuf, r3_w, r3_b, yg, res4);
  hipLaunchKernelGGL(k_final, dim3(64), dim3(128), 0, stream,
                     res4, x2, l1_w, l1_b, l3_w, l3_b, out);
}

// Round 3
// 264.367 us; speedup vs baseline: 1.0839x; 1.0335x over previous
//
#include <hip/hip_runtime.h>
#include <math.h>

#define B_ 64
#define N_ 512
#define P_ 256
#define E_ 4096
#define F_ 32
#define H_ 64
#define W_ 8
#define G_ 64
#define RH_ 256

// ---- workspace layout (float offsets) ----
#define X_OFF   0
#define T4_OFF  (X_OFF + N_*B_*F_)       // x:  [n][b][f]
#define T3_OFF  (T4_OFF + N_*B_*H_)      // t4: [n][b][h] (t2 folded in)
#define KB_OFF  (T3_OFF + P_*B_*H_)      // t3: [p][b][h]
#define KW_OFF  (KB_OFF + E_*H_)         // kb: [e][h]
#define YG_OFF  (KW_OFF + E_*B_*W_)      // kw: [e][b][w]
#define HB_OFF  (YG_OFF + B_*P_*G_)      // yg: [b][p*64+g]
#define RES_OFF (HB_OFF + B_*RH_)        // hbuf: [b][rh]
#define INT_OFF (RES_OFF + 4*B_*G_)      // res4: [pq][b][g]  (4 partials)
// int region at INT_OFF: lidx[4096] | ridx[4096] | part_start[512] | part_edges[4096]
// NOTE: r0 partials (256*16384 floats = 16 MB) alias X_OFF..KW region — those
// buffers (x, t4, t3, kb, kw) are dead once k_agg_gc has run.

// ---------------------------------------------------------------------------
__global__ __launch_bounds__(256) void k_decode(const float* __restrict__ linc,
    const float* __restrict__ rinc, int* __restrict__ lidx, int* __restrict__ ridx) {
  int i4 = blockIdx.x * 256 + threadIdx.x;
  const int L4 = (P_ * E_) / 4;  // 262144
  if (i4 < L4) {
    float4 v = ((const float4*)linc)[i4];
    int i = i4 * 4;
    int p = i >> 12, e = i & 4095;
    if (v.x != 0.0f) lidx[e]     = p;
    if (v.y != 0.0f) lidx[e + 1] = p;
    if (v.z != 0.0f) lidx[e + 2] = p;
    if (v.w != 0.0f) lidx[e + 3] = p;
  } else {
    int j4 = i4 - L4;
    float4 v = ((const float4*)rinc)[j4];
    int j = j4 * 4;
    int e = j >> 9, n = j & 511;
    if (v.x != 0.0f) ridx[e] = n;
    if (v.y != 0.0f) ridx[e] = n + 1;
    if (v.z != 0.0f) ridx[e] = n + 2;
    if (v.w != 0.0f) ridx[e] = n + 3;
  }
}

// Counting-sort edges by partition. Single block of 1024.
__global__ __launch_bounds__(1024) void k_lists(const int* __restrict__ lidx,
    int* __restrict__ part_start, int* __restrict__ part_edges) {
  __shared__ int cnt[256];
  __shared__ int buf[256];
  __shared__ int cur[256];
  int t = threadIdx.x;
  if (t < 256) cnt[t] = 0;
  __syncthreads();
  for (int e = t; e < E_; e += 1024) atomicAdd(&cnt[lidx[e]], 1);
  __syncthreads();
  if (t < 256) buf[t] = cnt[t];
  __syncthreads();
  for (int off = 1; off < 256; off <<= 1) {
    int add = 0;
    if (t < 256 && t >= off) add = buf[t - off];
    __syncthreads();
    if (t < 256) buf[t] += add;
    __syncthreads();
  }
  if (t < 256) {
    part_start[t + 1] = buf[t];
    if (t == 0) part_start[0] = 0;
    cur[t] = buf[t] - cnt[t];
  }
  __syncthreads();
  for (int e = t; e < E_; e += 1024) {
    int p = lidx[e];
    int pos = atomicAdd(&cur[p], 1);
    part_edges[pos] = e;
  }
}

// Grouped conv (K=16, VALID, 1 out pos) + bias + relu -> x[n][b][f]
__global__ __launch_bounds__(256) void k_conv(const float* __restrict__ x1,
    const float* __restrict__ conv_w, const float* __restrict__ conv_b,
    float* __restrict__ x) {
  __shared__ float wsm[32 * 132];
  __shared__ float xsm[8192];
  int n = blockIdx.x, t = threadIdx.x;
  for (int i = t; i < 1024; i += 256) {
    int f = i >> 5, j = i & 31;
    ((float4*)wsm)[f * 33 + j] = ((const float4*)(conv_w + n * 4096))[i];
  }
  for (int i = t; i < 2048; i += 256) {
    int b = i >> 5, j = i & 31;
    ((float4*)xsm)[i] = ((const float4*)(x1 + b * 65536 + n * 128))[j];
  }
  __syncthreads();
  int f = t & 31, bq = t >> 5;
  float cb = conv_b[n * 32 + f];
  float acc[8];
#pragma unroll
  for (int bi = 0; bi < 8; bi++) acc[bi] = cb;
  const float4* wf4 = (const float4*)wsm + f * 33;
  const float4* xb4 = (const float4*)xsm + bq * 256;
#pragma unroll 4
  for (int k4 = 0; k4 < 32; k4++) {
    float4 wv = wf4[k4];
#pragma unroll
    for (int bi = 0; bi < 8; bi++) {
      float4 xv = xb4[bi * 32 + k4];
      acc[bi] += wv.x * xv.x + wv.y * xv.y + wv.z * xv.z + wv.w * xv.w;
    }
  }
#pragma unroll
  for (int bi = 0; bi < 8; bi++) {
    int b = bq * 8 + bi;
    x[n * 2048 + b * 32 + f] = fmaxf(acc[bi], 0.0f);
  }
}

// blocks [0,512): t4[n][b][h] = x[n]@k4_w^T + x2@k2_w^T
// blocks [512,768): t3[p][b][h] = x[pidx[p]]@k3_w^T
// blocks [768,1792): kb[e][h] = ef[e,:8]@k1_w^T + k1_b
// blocks [1792,1856): hbuf[b][rh] = x2@r1_w^T + r1_b + cap@r2_w^T
__global__ __launch_bounds__(256) void k_prep(
    const float* __restrict__ x, const int* __restrict__ pidx,
    const float* __restrict__ k3_w, const float* __restrict__ k4_w,
    const float* __restrict__ x2, const float* __restrict__ k2_w,
    const float* __restrict__ ef, const float* __restrict__ k1_w,
    const float* __restrict__ k1_b,
    const float* __restrict__ r1_w, const float* __restrict__ r1_b,
    const float* __restrict__ r2_w, const float* __restrict__ cap,
    float* __restrict__ t4, float* __restrict__ t3, float* __restrict__ kb,
    float* __restrict__ hbuf) {
  __shared__ float xsh[2048];
  __shared__ float wsh[64 * 36];
  __shared__ float x2s[512];
  __shared__ float k2s[512];
  int blk = blockIdx.x, t = threadIdx.x;
  if (blk < 768) {
    bool isT4 = blk < 512;
    int n = isT4 ? blk : pidx[blk - 512];
    const float* wmat = isT4 ? k4_w : k3_w;
    float* outp = isT4 ? (t4 + blk * 4096) : (t3 + (blk - 512) * 4096);
    for (int i = t; i < 512; i += 256) {
      ((float4*)xsh)[i] = ((const float4*)(x + n * 2048))[i];
      int h = i >> 3, j = i & 7;
      ((float4*)wsh)[h * 9 + j] = ((const float4*)wmat)[i];
    }
    if (isT4) {
      for (int i = t; i < 128; i += 256) {
        ((float4*)x2s)[i] = ((const float4*)x2)[i];
        ((float4*)k2s)[i] = ((const float4*)k2_w)[i];
      }
    }
    __syncthreads();
    int h = t & 63, bq = t >> 6;
    float wreg[32];
#pragma unroll
    for (int j = 0; j < 8; j++) {
      float4 v = ((float4*)wsh)[h * 9 + j];
      wreg[4 * j] = v.x; wreg[4 * j + 1] = v.y; wreg[4 * j + 2] = v.z; wreg[4 * j + 3] = v.w;
    }
    float w2[8];
    if (isT4) {
      float4 u = ((float4*)k2s)[h * 2], v = ((float4*)k2s)[h * 2 + 1];
      w2[0] = u.x; w2[1] = u.y; w2[2] = u.z; w2[3] = u.w;
      w2[4] = v.x; w2[5] = v.y; w2[6] = v.z; w2[7] = v.w;
    }
    for (int bi = 0; bi < 16; bi++) {
      int b = bq * 16 + bi;
      float acc = 0.0f;
#pragma unroll
      for (int j = 0; j < 8; j++) {
        float4 xv = ((float4*)xsh)[b * 8 + j];
        acc += xv.x * wreg[4 * j] + xv.y * wreg[4 * j + 1] +
               xv.z * wreg[4 * j + 2] + xv.w * wreg[4 * j + 3];
      }
      if (isT4) {
        float4 u = ((float4*)x2s)[b * 2], v = ((float4*)x2s)[b * 2 + 1];
        acc += u.x * w2[0] + u.y * w2[1] + u.z * w2[2] + u.w * w2[3] +
               v.x * w2[4] + v.y * w2[5] + v.z * w2[6] + v.w * w2[7];
      }
      outp[b * 64 + h] = acc;
    }
  } else if (blk < 1792) {
    int o = (blk - 768) * 256 + t;
    int e = o >> 6, h = o & 63;
    float acc = k1_b[h];
    const float* er = ef + e * 9;
    const float* kr = k1_w + h * 8;
#pragma unroll
    for (int d = 0; d < 8; d++) acc += er[d] * kr[d];
    kb[o] = acc;
  } else {
    int o = (blk - 1792) * 256 + t;
    int rh = o & 255;
    float acc = r1_b[rh];
    const float* xr = x2 + (o >> 8) * 8;
    const float* rr = r1_w + rh * 8;
#pragma unroll
    for (int d = 0; d < 8; d++) acc += xr[d] * rr[d];
    const float* r2r = r2_w + rh * 256;
    for (int p4 = 0; p4 < 64; p4++) {
      float4 cv = ((const float4*)cap)[p4];
      float4 rv = ((const float4*)r2r)[p4];
      acc += cv.x * rv.x + cv.y * rv.y + cv.z * rv.z + cv.w * rv.w;
    }
    hbuf[o] = acc;
  }
}

// Per-edge: kern = kb[e]+t3[lidx]+t4[ridx]; leaky(0.02); @k5_w^T + k5_b; relu -> kw[e][b][w]
// 4 edges per block (amortizes k5t staging + dispatch).
__global__ __launch_bounds__(256) void k_edge(
    const float* __restrict__ kb, const float* __restrict__ t3,
    const float* __restrict__ t4, const float* __restrict__ k5_w,
    const float* __restrict__ k5_b, const int* __restrict__ lidx,
    const int* __restrict__ ridx, float* __restrict__ kw) {
  __shared__ float k5t[4 * 520];
  int e0 = blockIdx.x * 4, t = threadIdx.x;
  for (int i = t; i < 512; i += 256) {
    int h = i >> 3, w = i & 7;
    float v = k5_w[w * 64 + h];
#pragma unroll
    for (int qq = 0; qq < 4; qq++) k5t[qq * 520 + i] = v;
  }
  int q = t & 3, b = t >> 2;
  const float* kq = k5t + q * 520 + q * 128;
  float kb5_0 = k5_b[2 * q], kb5_1 = k5_b[2 * q + 1];
  __syncthreads();
  for (int ei = 0; ei < 4; ei++) {
    int e = e0 + ei;
    int p = lidx[e], r = ridx[e];
    const float4* kb4 = (const float4*)(kb + e * 64 + q * 16);
    const float4* t34 = (const float4*)(t3 + p * 4096 + b * 64 + q * 16);
    const float4* t44 = (const float4*)(t4 + r * 4096 + b * 64 + q * 16);
    float lk[16];
#pragma unroll
    for (int j4 = 0; j4 < 4; j4++) {
      float4 a = kb4[j4], c = t34[j4], d = t44[j4];
      float v;
      v = a.x + c.x + d.x; lk[j4 * 4 + 0] = v > 0.0f ? v : 0.02f * v;
      v = a.y + c.y + d.y; lk[j4 * 4 + 1] = v > 0.0f ? v : 0.02f * v;
      v = a.z + c.z + d.z; lk[j4 * 4 + 2] = v > 0.0f ? v : 0.02f * v;
      v = a.w + c.w + d.w; lk[j4 * 4 + 3] = v > 0.0f ? v : 0.02f * v;
    }
    float pw[8] = {0, 0, 0, 0, 0, 0, 0, 0};
#pragma unroll
    for (int j = 0; j < 16; j++) {
      float4 u = *(const float4*)(kq + j * 8);
      float4 v = *(const float4*)(kq + j * 8 + 4);
      float l = lk[j];
      pw[0] += l * u.x; pw[1] += l * u.y; pw[2] += l * u.z; pw[3] += l * u.w;
      pw[4] += l * v.x; pw[5] += l * v.y; pw[6] += l * v.z; pw[7] += l * v.w;
    }
#pragma unroll
    for (int w = 0; w < 8; w++) {
      pw[w] += __shfl_xor(pw[w], 1);
      pw[w] += __shfl_xor(pw[w], 2);
    }
    float2 o;
    o.x = fmaxf(pw[2 * q] + kb5_0, 0.0f);
    o.y = fmaxf(pw[2 * q + 1] + kb5_1, 0.0f);
    *(float2*)(kw + e * 512 + t * 2) = o;
  }
}

// Per-partition p: acc[b][k] (regs) = sum_e kw[e,b,w]*x[ridx[e],b,f]  (k = w*32+f);
// -> LDS bf16 accS[b][k] (oct-swizzled), then 4 g-split waves compute
// yg[b][p*64+g] = relu(accS[b,:] . gc_w[g,:] + gc_b[g]) with 8b x 2g register tiles.
__global__ __launch_bounds__(256) void k_agg_gc(const float* __restrict__ x,
    const float* __restrict__ kw, const int* __restrict__ ridx,
    const int* __restrict__ part_start, const int* __restrict__ part_edges,
    const float* __restrict__ gc_w, const float* __restrict__ gc_b,
    float* __restrict__ yg) {
  __shared__ unsigned short accS[64 * 256];  // bf16 [b][k], oct' = oct ^ (b>>3)
  int p = blockIdx.x, t = threadIdx.x;
  int b = t >> 2, s = t & 3;   // b in [0,64), s selects k-range [s*64, s*64+64)
  float acc[64];
#pragma unroll
  for (int j = 0; j < 64; j++) acc[j] = 0.0f;
  int s0 = part_start[p], s1 = part_start[p + 1];
  int idx = s0;
  for (; idx + 1 < s1; idx += 2) {
    int e0 = part_edges[idx], e1 = part_edges[idx + 1];
    int r0 = ridx[e0], r1 = ridx[e1];
    float2 ka = *(const float2*)(kw + e0 * 512 + b * 8 + s * 2);
    float2 kc = *(const float2*)(kw + e1 * 512 + b * 8 + s * 2);
    const float4* xp0 = (const float4*)(x + r0 * 2048 + b * 32);
    const float4* xp1 = (const float4*)(x + r1 * 2048 + b * 32);
    float xa[32], xb[32];
#pragma unroll
    for (int i = 0; i < 8; i++) {
      float4 v = xp0[i];
      xa[4 * i] = v.x; xa[4 * i + 1] = v.y; xa[4 * i + 2] = v.z; xa[4 * i + 3] = v.w;
    }
#pragma unroll
    for (int i = 0; i < 8; i++) {
      float4 v = xp1[i];
      xb[4 * i] = v.x; xb[4 * i + 1] = v.y; xb[4 * i + 2] = v.z; xb[4 * i + 3] = v.w;
    }
#pragma unroll
    for (int j = 0; j < 32; j++) acc[j] += ka.x * xa[j];
#pragma unroll
    for (int j = 0; j < 32; j++) acc[32 + j] += ka.y * xa[j];
#pragma unroll
    for (int j = 0; j < 32; j++) acc[j] += kc.x * xb[j];
#pragma unroll
    for (int j = 0; j < 32; j++) acc[32 + j] += kc.y * xb[j];
  }
  if (idx < s1) {
    int e0 = part_edges[idx];
    int r0 = ridx[e0];
    float2 ka = *(const float2*)(kw + e0 * 512 + b * 8 + s * 2);
    const float4* xp0 = (const float4*)(x + r0 * 2048 + b * 32);
    float xa[32];
#pragma unroll
    for (int i = 0; i < 8; i++) {
      float4 v = xp0[i];
      xa[4 * i] = v.x; xa[4 * i + 1] = v.y; xa[4 * i + 2] = v.z; xa[4 * i + 3] = v.w;
    }
#pragma unroll
    for (int j = 0; j < 32; j++) acc[j] += ka.x * xa[j];
#pragma unroll
    for (int j = 0; j < 32; j++) acc[32 + j] += ka.y * xa[j];
  }
  // store acc -> accS (bf16, RNE, oct-swizzled)
#pragma unroll
  for (int o = 0; o < 8; o++) {
    int koct = s * 8 + o;
    int os = koct ^ (b >> 3);
    unsigned int wds[4];
#pragma unroll
    for (int h = 0; h < 4; h++) {
      unsigned int u0 = __float_as_uint(acc[o * 8 + 2 * h]);
      u0 = u0 + 0x7fffu + ((u0 >> 16) & 1u);
      unsigned int u1 = __float_as_uint(acc[o * 8 + 2 * h + 1]);
      u1 = u1 + 0x7fffu + ((u1 >> 16) & 1u);
      wds[h] = (u0 >> 16) | (u1 & 0xffff0000u);
    }
    int4 pk = make_int4((int)wds[0], (int)wds[1], (int)wds[2], (int)wds[3]);
    *(int4*)(accS + b * 256 + os * 8) = pk;
  }
  __syncthreads();
  // epilogue: wave w handles g in [w*16, w*16+16)
  int lane = t & 63, wv = t >> 6;
  int bg = lane >> 3, gg = lane & 7;
  int g0 = wv * 16 + gg * 2;
  const float* gw0 = gc_w + g0 * 256;
  const float* gw1 = gc_w + (g0 + 1) * 256;
  float ac[8][2];
#pragma unroll
  for (int i = 0; i < 8; i++) { ac[i][0] = 0.0f; ac[i][1] = 0.0f; }
  for (int oct = 0; oct < 32; oct++) {
    int4 a8[8];
#pragma unroll
    for (int i = 0; i < 8; i++) {
      int row = bg * 8 + i;
      int os = oct ^ bg;
      a8[i] = *(const int4*)(accS + row * 256 + os * 8);
    }
    float4 b0a = *(const float4*)(gw0 + oct * 8);
    float4 b0b = *(const float4*)(gw0 + oct * 8 + 4);
    float4 b1a = *(const float4*)(gw1 + oct * 8);
    float4 b1b = *(const float4*)(gw1 + oct * 8 + 4);
    float bv0[8] = {b0a.x, b0a.y, b0a.z, b0a.w, b0b.x, b0b.y, b0b.z, b0b.w};
    float bv1[8] = {b1a.x, b1a.y, b1a.z, b1a.w, b1b.x, b1b.y, b1b.z, b1b.w};
#pragma unroll
    for (int kk = 0; kk < 8; kk++) {
#pragma unroll
      for (int i = 0; i < 8; i++) {
        int w32;
        switch (kk >> 1) {
          case 0: w32 = a8[i].x; break;
          case 1: w32 = a8[i].y; break;
          case 2: w32 = a8[i].z; break;
          default: w32 = a8[i].w; break;
        }
        unsigned int u = (unsigned int)w32;
        unsigned int bits = (kk & 1) ? (u & 0xffff0000u) : (u << 16);
        float av = __uint_as_float(bits);
        ac[i][0] += av * bv0[kk];
        ac[i][1] += av * bv1[kk];
      }
    }
  }
  float gb0 = gc_b[g0], gb1 = gc_b[g0 + 1];
#pragma unroll
  for (int i = 0; i < 8; i++) {
    int bb = bg * 8 + i;
    float* yp = yg + bb * 16384 + p * 64;
    yp[g0]     = fmaxf(ac[i][0] + gb0, 0.0f);
    yp[g0 + 1] = fmaxf(ac[i][1] + gb1, 0.0f);
  }
}

// r0 GEMM partials: grid 256 = kc (Kc=64). Block computes full 64b x 256rh tile
// for its k-chunk via outer product; writes part[kc][b][rh].
// LDS: ygT[64k][68] (stride 68), wT[64k][260] (stride 260) — transposed-on-store.
__global__ __launch_bounds__(256) void k_r0(const float* __restrict__ yg,
    const float* __restrict__ r0_w, float* __restrict__ part) {
  __shared__ float ygs[64 * 68];   // ygT[k][b], row stride 68
  __shared__ float wts[64 * 260];  // wT[k][rh], row stride 260
  int kc = blockIdx.x, t = threadIdx.x;
  int k0 = kc * 64;
  // stage wT: 16 rounds, thread -> (rh = rd*16 + t>>4, c = t&15)
  {
    int rr = t >> 4, c = t & 15;
    for (int rd = 0; rd < 16; rd++) {
      int rh = rd * 16 + rr;
      float4 v = *(const float4*)(r0_w + rh * 16384 + k0 + c * 4);
      wts[(4 * c + 0) * 260 + rh] = v.x;
      wts[(4 * c + 1) * 260 + rh] = v.y;
      wts[(4 * c + 2) * 260 + rh] = v.z;
      wts[(4 * c + 3) * 260 + rh] = v.w;
    }
  }
  // stage ygT: thread -> (b = t>>2, kq = t&3 covering 16 k)
  {
    int b = t >> 2, kq = t & 3;
    const float* src = yg + b * 16384 + k0 + kq * 16;
#pragma unroll
    for (int u = 0; u < 4; u++) {
      float4 v = *(const float4*)(src + u * 4);
      int kk = kq * 16 + u * 4;
      ygs[(kk + 0) * 68 + b] = v.x;
      ygs[(kk + 1) * 68 + b] = v.y;
      ygs[(kk + 2) * 68 + b] = v.z;
      ygs[(kk + 3) * 68 + b] = v.w;
    }
  }
  __syncthreads();
  int lane = t & 63, wv = t >> 6;
  int b8 = lane & 7, r8 = lane >> 3;
  const float* yp = ygs + b8 * 8;
  const float* wp = wts + wv * 64 + r8 * 8;
  float acc[8][8];
#pragma unroll
  for (int i = 0; i < 8; i++)
#pragma unroll
    for (int j = 0; j < 8; j++) acc[i][j] = 0.0f;
#pragma unroll 2
  for (int k = 0; k < 64; k++) {
    float4 ya = *(const float4*)(yp + k * 68);
    float4 yb = *(const float4*)(yp + k * 68 + 4);
    float4 wa = *(const float4*)(wp + k * 260);
    float4 wb = *(const float4*)(wp + k * 260 + 4);
    float yv[8] = {ya.x, ya.y, ya.z, ya.w, yb.x, yb.y, yb.z, yb.w};
    float wr[8] = {wa.x, wa.y, wa.z, wa.w, wb.x, wb.y, wb.z, wb.w};
#pragma unroll
    for (int i = 0; i < 8; i++)
#pragma unroll
      for (int j = 0; j < 8; j++) acc[i][j] += yv[i] * wr[j];
  }
  float* pb = part + kc * 16384 + wv * 64 + r8 * 8;
#pragma unroll
  for (int i = 0; i < 8; i++) {
    float4 s0 = make_float4(acc[i][0], acc[i][1], acc[i][2], acc[i][3]);
    float4 s1 = make_float4(acc[i][4], acc[i][5], acc[i][6], acc[i][7]);
    float* pp = pb + (b8 * 8 + i) * 256;
    *(float4*)pp = s0;
    *(float4*)(pp + 4) = s1;
  }
}

// Reduce partials: grid 256 = (kq 4) x (oq 64). hbuf[o] += sum_{kc in kq} part[kc][o]
__global__ __launch_bounds__(256) void k_r0red(const float* __restrict__ part,
    float* __restrict__ hbuf) {
  int blk = blockIdx.x;
  int oq = blk & 63, kq = blk >> 6;
  int o = oq * 256 + threadIdx.x;
  float s = 0.0f;
  const float* pp = part + kq * 64 * 16384 + o;
#pragma unroll 8
  for (int kc = 0; kc < 64; kc++) s += pp[kc * 16384];
  atomicAdd(&hbuf[o], s);
}

// grid 256 = (bb, pq): wt for 64 p's, partial res over those p's -> res4[pq][b][g]
__global__ __launch_bounds__(256) void k_wt_res(const float* __restrict__ hbuf,
    const float* __restrict__ r3_w, const float* __restrict__ r3_b,
    const float* __restrict__ yg, float* __restrict__ res4) {
  __shared__ float hs[256];
  __shared__ float wts[64];
  __shared__ float red[256];
  int blk = blockIdx.x;
  int bb = blk >> 2, pq = blk & 3;
  int t = threadIdx.x;
  float hv = hbuf[bb * 256 + t];
  hs[t] = hv > 0.0f ? hv : 0.01f * hv;
  __syncthreads();
  int pl = t >> 2, c = t & 3;
  int pp = pq * 64 + pl;
  const float4* wrow = (const float4*)(r3_w + pp * 256 + c * 64);
  const float4* h4 = (const float4*)(hs) + c * 16;
  float a = 0.0f;
#pragma unroll
  for (int j = 0; j < 16; j++) {
    float4 w4 = wrow[j], hh = h4[j];
    a += hh.x * w4.x + hh.y * w4.y + hh.z * w4.z + hh.w * w4.w;
  }
  a += __shfl_xor(a, 1);
  a += __shfl_xor(a, 2);
  if (c == 0) wts[pl] = fmaxf(a + r3_b[pp], 0.0f);
  __syncthreads();
  int g = t & 63, ch = t >> 6;
  float r = 0.0f;
  const float* ygp = yg + bb * 16384 + pq * 4096 + g;
#pragma unroll
  for (int pi = 0; pi < 16; pi++) {
    int pl2 = ch * 16 + pi;
    r += wts[pl2] * ygp[pl2 * 64];
  }
  red[t] = r;
  __syncthreads();
  if (t < 64)
    res4[pq * 4096 + bb * 64 + t] = red[t] + red[t + 64] + red[t + 128] + red[t + 192];
}

// z = elu([sum(res4), x2] @ l1_w^T + l1_b); out = z @ l3_w^T + l3_b
__global__ __launch_bounds__(128) void k_final(const float* __restrict__ res4,
    const float* __restrict__ x2, const float* __restrict__ l1_w,
    const float* __restrict__ l1_b, const float* __restrict__ l3_w,
    const float* __restrict__ l3_b, float* __restrict__ out) {
  __shared__ float zs[128];
  int bb = blockIdx.x, t = threadIdx.x;
  float acc = l1_b[t];
  const float* wrow = l1_w + t * 72;
  const float* rr = res4 + bb * 64;
#pragma unroll 8
  for (int j = 0; j < 64; j++) {
    float rv = rr[j] + rr[4096 + j] + rr[8192 + j] + rr[12288 + j];
    acc += rv * wrow[j];
  }
  const float* xr = x2 + bb * 8;
#pragma unroll
  for (int j = 0; j < 8; j++) acc += xr[j] * wrow[64 + j];
  zs[t] = acc > 0.0f ? acc : expm1f(acc);
  __syncthreads();
  if (t < 9) {
    float o = l3_b[t];
    const float* w3 = l3_w + t * 128;
    for (int j = 0; j < 128; j++) o += zs[j] * w3[j];
    out[bb * 9 + t] = o;
  }
}

extern "C" void kernel_launch(void* const* d_in, const int* in_sizes, int n_in,
                              void* d_out, int out_size, void* d_ws, size_t ws_size,
                              hipStream_t stream) {
  (void)in_sizes; (void)n_in; (void)out_size; (void)ws_size;
  const float* x1     = (const float*)d_in[0];
  const float* x2     = (const float*)d_in[1];
  const float* conv_w = (const float*)d_in[2];
  const float* conv_b = (const float*)d_in[3];
  const float* k1_w   = (const float*)d_in[4];
  const float* k1_b   = (const float*)d_in[5];
  const float* k2_w   = (const float*)d_in[6];
  const float* k3_w   = (const float*)d_in[7];
  const float* k4_w   = (const float*)d_in[8];
  const float* k5_w   = (const float*)d_in[9];
  const float* k5_b   = (const float*)d_in[10];
  const float* gc_w   = (const float*)d_in[11];
  const float* gc_b   = (const float*)d_in[12];
  const float* r0_w   = (const float*)d_in[13];
  const float* r1_w   = (const float*)d_in[14];
  const float* r1_b   = (const float*)d_in[15];
  const float* r2_w   = (const float*)d_in[16];
  const float* r3_w   = (const float*)d_in[17];
  const float* r3_b   = (const float*)d_in[18];
  const float* l1_w   = (const float*)d_in[19];
  const float* l1_b   = (const float*)d_in[20];
  const float* l3_w   = (const float*)d_in[21];
  const float* l3_b   = (const float*)d_in[22];
  const float* ef     = (const float*)d_in[23];
  const float* linc   = (const float*)d_in[24];
  const float* rinc   = (const float*)d_in[25];
  const float* cap    = (const float*)d_in[26];
  const int*   pidx   = (const int*)d_in[27];
  float* out = (float*)d_out;

  float* ws   = (float*)d_ws;
  float* xbuf = ws + X_OFF;
  float* t4   = ws + T4_OFF;
  float* t3   = ws + T3_OFF;
  float* kb   = ws + KB_OFF;
  float* kwb  = ws + KW_OFF;
  float* yg   = ws + YG_OFF;
  float* hbuf = ws + HB_OFF;
  float* res4 = ws + RES_OFF;
  float* part = ws + X_OFF;   // aliases x/t4/t3/kb/kw (dead after k_agg_gc); 4.19M floats
  int* ib = (int*)(ws + INT_OFF);
  int* lidx = ib;
  int* ridx = ib + 4096;
  int* part_start = ib + 8192;
  int* part_edges = ib + 8704;

  hipLaunchKernelGGL(k_decode, dim3(3072), dim3(256), 0, stream, linc, rinc, lidx, ridx);
  hipLaunchKernelGGL(k_lists, dim3(1), dim3(1024), 0, stream, lidx, part_start, part_edges);
  hipLaunchKernelGGL(k_conv, dim3(512), dim3(256), 0, stream, x1, conv_w, conv_b, xbuf);
  hipLaunchKernelGGL(k_prep, dim3(1856), dim3(256), 0, stream,
                     xbuf, pidx, k3_w, k4_w, x2, k2_w, ef, k1_w, k1_b,
                     r1_w, r1_b, r2_w, cap, t4, t3, kb, hbuf);
  hipLaunchKernelGGL(k_edge, dim3(1024), dim3(256), 0, stream,
                     kb, t3, t4, k5_w, k5_b, lidx, ridx, kwb);
  hipLaunchKernelGGL(k_agg_gc, dim3(256), dim3(256), 0, stream,
                     xbuf, kwb, ridx, part_start, part_edges, gc_w, gc_b, yg);
  hipLaunchKernelGGL(k_r0, dim3(256), dim3(256), 0, stream, yg, r0_w, part);
  hipLaunchKernelGGL(k_r0red, dim3(256), dim3(256), 0, stream, part, hbuf);
  hipLaunchKernelGGL(k_wt_res, dim3(256), dim3(256), 0, stream, hbuf, r3_w, r3_b, yg, res4);
  hipLaunchKernelGGL(k_final, dim3(64), dim3(128), 0, stream,
                     res4, x2, l1_w, l1_b, l3_w, l3_b, out);
}

// Round 4
// 259.027 us; speedup vs baseline: 1.1062x; 1.0206x over previous
//
#include <hip/hip_runtime.h>
#include <math.h>

#define B_ 64
#define N_ 512
#define P_ 256
#define E_ 4096
#define F_ 32
#define H_ 64
#define W_ 8
#define G_ 64
#define RH_ 256

// ---- workspace layout (float offsets) ----
#define X_OFF   0
#define T4_OFF  (X_OFF + N_*B_*F_)       // x:  [n][b][f]
#define T3_OFF  (T4_OFF + N_*B_*H_)      // t4: [n][b][h] (t2 folded in)
#define KB_OFF  (T3_OFF + P_*B_*H_)      // t3: [p][b][h]
#define KW_OFF  (KB_OFF + E_*H_)         // kb: [e][h]
#define YG_OFF  (KW_OFF + E_*B_*W_)      // (kw slot unused now, kept for layout stability)
#define HB_OFF  (YG_OFF + B_*P_*G_)      // yg: [b][p*64+g]
#define RES_OFF (HB_OFF + B_*RH_)        // hbuf: [b][rh]
#define INT_OFF (RES_OFF + 4*B_*G_)      // res4: [pq][b][g]
// int region at INT_OFF: lidx[4096] | ridx[4096] | part_start[512] | part_edges[4096]
// r0 partials (256*16384 floats = 16 MB) alias X_OFF.. (x/t4/t3/kb dead after k_eagg)

// ---------------------------------------------------------------------------
__global__ __launch_bounds__(256) void k_decode(const float* __restrict__ linc,
    const float* __restrict__ rinc, int* __restrict__ lidx, int* __restrict__ ridx) {
  int i4 = blockIdx.x * 256 + threadIdx.x;
  const int L4 = (P_ * E_) / 4;  // 262144
  if (i4 < L4) {
    float4 v = ((const float4*)linc)[i4];
    int i = i4 * 4;
    int p = i >> 12, e = i & 4095;
    if (v.x != 0.0f) lidx[e]     = p;
    if (v.y != 0.0f) lidx[e + 1] = p;
    if (v.z != 0.0f) lidx[e + 2] = p;
    if (v.w != 0.0f) lidx[e + 3] = p;
  } else {
    int j4 = i4 - L4;
    float4 v = ((const float4*)rinc)[j4];
    int j = j4 * 4;
    int e = j >> 9, n = j & 511;
    if (v.x != 0.0f) ridx[e] = n;
    if (v.y != 0.0f) ridx[e] = n + 1;
    if (v.z != 0.0f) ridx[e] = n + 2;
    if (v.w != 0.0f) ridx[e] = n + 3;
  }
}

// Counting-sort edges by partition. Single block of 1024.
__global__ __launch_bounds__(1024) void k_lists(const int* __restrict__ lidx,
    int* __restrict__ part_start, int* __restrict__ part_edges) {
  __shared__ int cnt[256];
  __shared__ int buf[256];
  __shared__ int cur[256];
  int t = threadIdx.x;
  if (t < 256) cnt[t] = 0;
  __syncthreads();
  for (int e = t; e < E_; e += 1024) atomicAdd(&cnt[lidx[e]], 1);
  __syncthreads();
  if (t < 256) buf[t] = cnt[t];
  __syncthreads();
  for (int off = 1; off < 256; off <<= 1) {
    int add = 0;
    if (t < 256 && t >= off) add = buf[t - off];
    __syncthreads();
    if (t < 256) buf[t] += add;
    __syncthreads();
  }
  if (t < 256) {
    part_start[t + 1] = buf[t];
    if (t == 0) part_start[0] = 0;
    cur[t] = buf[t] - cnt[t];
  }
  __syncthreads();
  for (int e = t; e < E_; e += 1024) {
    int p = lidx[e];
    int pos = atomicAdd(&cur[p], 1);
    part_edges[pos] = e;
  }
}

// Grouped conv (K=16, VALID, 1 out pos) + bias + relu -> x[n][b][f]
__global__ __launch_bounds__(256) void k_conv(const float* __restrict__ x1,
    const float* __restrict__ conv_w, const float* __restrict__ conv_b,
    float* __restrict__ x) {
  __shared__ float wsm[32 * 132];
  __shared__ float xsm[8192];
  int n = blockIdx.x, t = threadIdx.x;
  for (int i = t; i < 1024; i += 256) {
    int f = i >> 5, j = i & 31;
    ((float4*)wsm)[f * 33 + j] = ((const float4*)(conv_w + n * 4096))[i];
  }
  for (int i = t; i < 2048; i += 256) {
    int b = i >> 5, j = i & 31;
    ((float4*)xsm)[i] = ((const float4*)(x1 + b * 65536 + n * 128))[j];
  }
  __syncthreads();
  int f = t & 31, bq = t >> 5;
  float cb = conv_b[n * 32 + f];
  float acc[8];
#pragma unroll
  for (int bi = 0; bi < 8; bi++) acc[bi] = cb;
  const float4* wf4 = (const float4*)wsm + f * 33;
  const float4* xb4 = (const float4*)xsm + bq * 256;
#pragma unroll 4
  for (int k4 = 0; k4 < 32; k4++) {
    float4 wv = wf4[k4];
#pragma unroll
    for (int bi = 0; bi < 8; bi++) {
      float4 xv = xb4[bi * 32 + k4];
      acc[bi] += wv.x * xv.x + wv.y * xv.y + wv.z * xv.z + wv.w * xv.w;
    }
  }
#pragma unroll
  for (int bi = 0; bi < 8; bi++) {
    int b = bq * 8 + bi;
    x[n * 2048 + b * 32 + f] = fmaxf(acc[bi], 0.0f);
  }
}

// blocks [0,512): t4[n][b][h] = x[n]@k4_w^T + x2@k2_w^T
// blocks [512,768): t3[p][b][h] = x[pidx[p]]@k3_w^T
// blocks [768,1792): kb[e][h] = ef[e,:8]@k1_w^T + k1_b
// blocks [1792,1856): hbuf[b][rh] = x2@r1_w^T + r1_b + cap@r2_w^T
__global__ __launch_bounds__(256) void k_prep(
    const float* __restrict__ x, const int* __restrict__ pidx,
    const float* __restrict__ k3_w, const float* __restrict__ k4_w,
    const float* __restrict__ x2, const float* __restrict__ k2_w,
    const float* __restrict__ ef, const float* __restrict__ k1_w,
    const float* __restrict__ k1_b,
    const float* __restrict__ r1_w, const float* __restrict__ r1_b,
    const float* __restrict__ r2_w, const float* __restrict__ cap,
    float* __restrict__ t4, float* __restrict__ t3, float* __restrict__ kb,
    float* __restrict__ hbuf) {
  __shared__ float xsh[2048];
  __shared__ float wsh[64 * 36];
  __shared__ float x2s[512];
  __shared__ float k2s[512];
  int blk = blockIdx.x, t = threadIdx.x;
  if (blk < 768) {
    bool isT4 = blk < 512;
    int n = isT4 ? blk : pidx[blk - 512];
    const float* wmat = isT4 ? k4_w : k3_w;
    float* outp = isT4 ? (t4 + blk * 4096) : (t3 + (blk - 512) * 4096);
    for (int i = t; i < 512; i += 256) {
      ((float4*)xsh)[i] = ((const float4*)(x + n * 2048))[i];
      int h = i >> 3, j = i & 7;
      ((float4*)wsh)[h * 9 + j] = ((const float4*)wmat)[i];
    }
    if (isT4) {
      for (int i = t; i < 128; i += 256) {
        ((float4*)x2s)[i] = ((const float4*)x2)[i];
        ((float4*)k2s)[i] = ((const float4*)k2_w)[i];
      }
    }
    __syncthreads();
    int h = t & 63, bq = t >> 6;
    float wreg[32];
#pragma unroll
    for (int j = 0; j < 8; j++) {
      float4 v = ((float4*)wsh)[h * 9 + j];
      wreg[4 * j] = v.x; wreg[4 * j + 1] = v.y; wreg[4 * j + 2] = v.z; wreg[4 * j + 3] = v.w;
    }
    float w2[8];
    if (isT4) {
      float4 u = ((float4*)k2s)[h * 2], v = ((float4*)k2s)[h * 2 + 1];
      w2[0] = u.x; w2[1] = u.y; w2[2] = u.z; w2[3] = u.w;
      w2[4] = v.x; w2[5] = v.y; w2[6] = v.z; w2[7] = v.w;
    }
    for (int bi = 0; bi < 16; bi++) {
      int b = bq * 16 + bi;
      float acc = 0.0f;
#pragma unroll
      for (int j = 0; j < 8; j++) {
        float4 xv = ((float4*)xsh)[b * 8 + j];
        acc += xv.x * wreg[4 * j] + xv.y * wreg[4 * j + 1] +
               xv.z * wreg[4 * j + 2] + xv.w * wreg[4 * j + 3];
      }
      if (isT4) {
        float4 u = ((float4*)x2s)[b * 2], v = ((float4*)x2s)[b * 2 + 1];
        acc += u.x * w2[0] + u.y * w2[1] + u.z * w2[2] + u.w * w2[3] +
               v.x * w2[4] + v.y * w2[5] + v.z * w2[6] + v.w * w2[7];
      }
      outp[b * 64 + h] = acc;
    }
  } else if (blk < 1792) {
    int o = (blk - 768) * 256 + t;
    int e = o >> 6, h = o & 63;
    float acc = k1_b[h];
    const float* er = ef + e * 9;
    const float* kr = k1_w + h * 8;
#pragma unroll
    for (int d = 0; d < 8; d++) acc += er[d] * kr[d];
    kb[o] = acc;
  } else {
    int o = (blk - 1792) * 256 + t;
    int rh = o & 255;
    float acc = r1_b[rh];
    const float* xr = x2 + (o >> 8) * 8;
    const float* rr = r1_w + rh * 8;
#pragma unroll
    for (int d = 0; d < 8; d++) acc += xr[d] * rr[d];
    const float* r2r = r2_w + rh * 256;
    for (int p4 = 0; p4 < 64; p4++) {
      float4 cv = ((const float4*)cap)[p4];
      float4 rv = ((const float4*)r2r)[p4];
      acc += cv.x * rv.x + cv.y * rv.y + cv.z * rv.z + cv.w * rv.w;
    }
    hbuf[o] = acc;
  }
}

// Fused edge-MLP + aggregation + gc GEMM, one block per partition p.
// Per edge e in partition: kern[b][h] = kb[e][h] + t3s[b][h] + t4[r][b][h];
// leaky(0.02); v[b][w] = relu(kern . k5_w[w] + k5_b[w]); acc[b][wf] += v*x[r][b][f].
// Then acc -> bf16 LDS, 4 g-split waves compute yg = relu(acc . gc_w + gc_b).
__global__ __launch_bounds__(256) void k_eagg(
    const float* __restrict__ x, const float* __restrict__ kb,
    const float* __restrict__ t3, const float* __restrict__ t4,
    const float* __restrict__ k5_w, const float* __restrict__ k5_b,
    const int* __restrict__ ridx, const int* __restrict__ part_start,
    const int* __restrict__ part_edges,
    const float* __restrict__ gc_w, const float* __restrict__ gc_b,
    float* __restrict__ yg) {
  __shared__ float t3s[64 * 68];             // [b][h], stride 68 (bank-spread)
  __shared__ float k5t[4 * 520];             // s-replicated [h][w]
  __shared__ unsigned short accS[64 * 256];  // bf16 [b][k], oct ^ (b>>3) swizzle
  int p = blockIdx.x, t = threadIdx.x;
  for (int i = t; i < 512; i += 256) {
    int h = i >> 3, w = i & 7;
    float v = k5_w[w * 64 + h];
#pragma unroll
    for (int qq = 0; qq < 4; qq++) k5t[qq * 520 + i] = v;
  }
  for (int i4 = t; i4 < 1024; i4 += 256) {
    float4 v = ((const float4*)(t3 + p * 4096))[i4];
    *(float4*)(t3s + (i4 >> 4) * 68 + (i4 & 15) * 4) = v;
  }
  __syncthreads();
  int s = t & 3, b = t >> 2;
  const float* kq = k5t + s * 520 + s * 128;  // rows h = s*16..s*16+15
  float kb5_0 = k5_b[2 * s], kb5_1 = k5_b[2 * s + 1];
  const float4* t3p = (const float4*)(t3s + b * 68 + s * 16);
  float acc[64];
#pragma unroll
  for (int j = 0; j < 64; j++) acc[j] = 0.0f;
  int s0 = part_start[p], s1 = part_start[p + 1];
  int e = 0, r = 0;
  if (s0 < s1) { e = part_edges[s0]; r = ridx[e]; }
  for (int idx = s0; idx < s1; idx++) {
    int e_n = 0, r_n = 0;
    if (idx + 1 < s1) { e_n = part_edges[idx + 1]; r_n = ridx[e_n]; }
    // issue x-row loads early (independent of kern math)
    const float4* xp = (const float4*)(x + r * 2048 + b * 32);
    float4 xv0 = xp[0], xv1 = xp[1], xv2 = xp[2], xv3 = xp[3];
    float4 xv4 = xp[4], xv5 = xp[5], xv6 = xp[6], xv7 = xp[7];
    const float4* kb4 = (const float4*)(kb + e * 64 + s * 16);
    const float4* t44 = (const float4*)(t4 + r * 4096 + b * 64 + s * 16);
    float lk[16];
#pragma unroll
    for (int j4 = 0; j4 < 4; j4++) {
      float4 a = kb4[j4], c = t3p[j4], d = t44[j4];
      float v;
      v = a.x + c.x + d.x; lk[j4 * 4 + 0] = v > 0.0f ? v : 0.02f * v;
      v = a.y + c.y + d.y; lk[j4 * 4 + 1] = v > 0.0f ? v : 0.02f * v;
      v = a.z + c.z + d.z; lk[j4 * 4 + 2] = v > 0.0f ? v : 0.02f * v;
      v = a.w + c.w + d.w; lk[j4 * 4 + 3] = v > 0.0f ? v : 0.02f * v;
    }
    float pw[8] = {0, 0, 0, 0, 0, 0, 0, 0};
#pragma unroll
    for (int j = 0; j < 16; j++) {
      float4 u = *(const float4*)(kq + j * 8);
      float4 v = *(const float4*)(kq + j * 8 + 4);
      float l = lk[j];
      pw[0] += l * u.x; pw[1] += l * u.y; pw[2] += l * u.z; pw[3] += l * u.w;
      pw[4] += l * v.x; pw[5] += l * v.y; pw[6] += l * v.z; pw[7] += l * v.w;
    }
#pragma unroll
    for (int w = 0; w < 8; w++) {  // reduce over the 4 s-lanes
      pw[w] += __shfl_xor(pw[w], 1);
      pw[w] += __shfl_xor(pw[w], 2);
    }
    float kv0 = fmaxf(pw[2 * s] + kb5_0, 0.0f);
    float kv1 = fmaxf(pw[2 * s + 1] + kb5_1, 0.0f);
    float xa[32];
    xa[0] = xv0.x; xa[1] = xv0.y; xa[2] = xv0.z; xa[3] = xv0.w;
    xa[4] = xv1.x; xa[5] = xv1.y; xa[6] = xv1.z; xa[7] = xv1.w;
    xa[8] = xv2.x; xa[9] = xv2.y; xa[10] = xv2.z; xa[11] = xv2.w;
    xa[12] = xv3.x; xa[13] = xv3.y; xa[14] = xv3.z; xa[15] = xv3.w;
    xa[16] = xv4.x; xa[17] = xv4.y; xa[18] = xv4.z; xa[19] = xv4.w;
    xa[20] = xv5.x; xa[21] = xv5.y; xa[22] = xv5.z; xa[23] = xv5.w;
    xa[24] = xv6.x; xa[25] = xv6.y; xa[26] = xv6.z; xa[27] = xv6.w;
    xa[28] = xv7.x; xa[29] = xv7.y; xa[30] = xv7.z; xa[31] = xv7.w;
#pragma unroll
    for (int j = 0; j < 32; j++) acc[j] += kv0 * xa[j];
#pragma unroll
    for (int j = 0; j < 32; j++) acc[32 + j] += kv1 * xa[j];
    e = e_n; r = r_n;
  }
  // store acc -> accS (bf16, RNE, oct-swizzled). Thread's k-range = [s*64, s*64+64)
#pragma unroll
  for (int o = 0; o < 8; o++) {
    int koct = s * 8 + o;
    int os = koct ^ (b >> 3);
    unsigned int wds[4];
#pragma unroll
    for (int h = 0; h < 4; h++) {
      unsigned int u0 = __float_as_uint(acc[o * 8 + 2 * h]);
      u0 = u0 + 0x7fffu + ((u0 >> 16) & 1u);
      unsigned int u1 = __float_as_uint(acc[o * 8 + 2 * h + 1]);
      u1 = u1 + 0x7fffu + ((u1 >> 16) & 1u);
      wds[h] = (u0 >> 16) | (u1 & 0xffff0000u);
    }
    int4 pk = make_int4((int)wds[0], (int)wds[1], (int)wds[2], (int)wds[3]);
    *(int4*)(accS + b * 256 + os * 8) = pk;
  }
  __syncthreads();
  // epilogue: wave wv handles g in [wv*16, wv*16+16)
  int lane = t & 63, wv = t >> 6;
  int bg = lane >> 3, gg = lane & 7;
  int g0 = wv * 16 + gg * 2;
  const float* gw0 = gc_w + g0 * 256;
  const float* gw1 = gc_w + (g0 + 1) * 256;
  float ac[8][2];
#pragma unroll
  for (int i = 0; i < 8; i++) { ac[i][0] = 0.0f; ac[i][1] = 0.0f; }
  for (int oct = 0; oct < 32; oct++) {
    int4 a8[8];
#pragma unroll
    for (int i = 0; i < 8; i++) {
      int row = bg * 8 + i;
      int os = oct ^ bg;
      a8[i] = *(const int4*)(accS + row * 256 + os * 8);
    }
    float4 b0a = *(const float4*)(gw0 + oct * 8);
    float4 b0b = *(const float4*)(gw0 + oct * 8 + 4);
    float4 b1a = *(const float4*)(gw1 + oct * 8);
    float4 b1b = *(const float4*)(gw1 + oct * 8 + 4);
    float bv0[8] = {b0a.x, b0a.y, b0a.z, b0a.w, b0b.x, b0b.y, b0b.z, b0b.w};
    float bv1[8] = {b1a.x, b1a.y, b1a.z, b1a.w, b1b.x, b1b.y, b1b.z, b1b.w};
#pragma unroll
    for (int kk = 0; kk < 8; kk++) {
#pragma unroll
      for (int i = 0; i < 8; i++) {
        int w32;
        switch (kk >> 1) {
          case 0: w32 = a8[i].x; break;
          case 1: w32 = a8[i].y; break;
          case 2: w32 = a8[i].z; break;
          default: w32 = a8[i].w; break;
        }
        unsigned int u = (unsigned int)w32;
        unsigned int bits = (kk & 1) ? (u & 0xffff0000u) : (u << 16);
        float av = __uint_as_float(bits);
        ac[i][0] += av * bv0[kk];
        ac[i][1] += av * bv1[kk];
      }
    }
  }
  float gb0 = gc_b[g0], gb1 = gc_b[g0 + 1];
#pragma unroll
  for (int i = 0; i < 8; i++) {
    int bb = bg * 8 + i;
    float* yp = yg + bb * 16384 + p * 64;
    yp[g0]     = fmaxf(ac[i][0] + gb0, 0.0f);
    yp[g0 + 1] = fmaxf(ac[i][1] + gb1, 0.0f);
  }
}

// r0 GEMM partials: grid 256 = kc (Kc=64). Block computes full 64b x 256rh tile
// for its k-chunk via outer product; writes part[kc][b][rh].
__global__ __launch_bounds__(256) void k_r0(const float* __restrict__ yg,
    const float* __restrict__ r0_w, float* __restrict__ part) {
  __shared__ float ygs[64 * 68];   // ygT[k][b], row stride 68
  __shared__ float wts[64 * 260];  // wT[k][rh], row stride 260
  int kc = blockIdx.x, t = threadIdx.x;
  int k0 = kc * 64;
  // stage wT: c = t>>4 selects k-group (store lanes spread 32 banks), rr = t&15
  {
    int c = t >> 4, rr = t & 15;
    for (int rd = 0; rd < 16; rd++) {
      int rh = rd * 16 + rr;
      float4 v = *(const float4*)(r0_w + rh * 16384 + k0 + c * 4);
      wts[(4 * c + 0) * 260 + rh] = v.x;
      wts[(4 * c + 1) * 260 + rh] = v.y;
      wts[(4 * c + 2) * 260 + rh] = v.z;
      wts[(4 * c + 3) * 260 + rh] = v.w;
    }
  }
  // stage ygT
  {
    int b = t >> 2, kq = t & 3;
    const float* src = yg + b * 16384 + k0 + kq * 16;
#pragma unroll
    for (int u = 0; u < 4; u++) {
      float4 v = *(const float4*)(src + u * 4);
      int kk = kq * 16 + u * 4;
      ygs[(kk + 0) * 68 + b] = v.x;
      ygs[(kk + 1) * 68 + b] = v.y;
      ygs[(kk + 2) * 68 + b] = v.z;
      ygs[(kk + 3) * 68 + b] = v.w;
    }
  }
  __syncthreads();
  int lane = t & 63, wv = t >> 6;
  int b8 = lane & 7, r8 = lane >> 3;
  const float* yp = ygs + b8 * 8;
  const float* wp = wts + wv * 64 + r8 * 8;
  float acc[8][8];
#pragma unroll
  for (int i = 0; i < 8; i++)
#pragma unroll
    for (int j = 0; j < 8; j++) acc[i][j] = 0.0f;
#pragma unroll 2
  for (int k = 0; k < 64; k++) {
    float4 ya = *(const float4*)(yp + k * 68);
    float4 yb = *(const float4*)(yp + k * 68 + 4);
    float4 wa = *(const float4*)(wp + k * 260);
    float4 wb = *(const float4*)(wp + k * 260 + 4);
    float yv[8] = {ya.x, ya.y, ya.z, ya.w, yb.x, yb.y, yb.z, yb.w};
    float wr[8] = {wa.x, wa.y, wa.z, wa.w, wb.x, wb.y, wb.z, wb.w};
#pragma unroll
    for (int i = 0; i < 8; i++)
#pragma unroll
      for (int j = 0; j < 8; j++) acc[i][j] += yv[i] * wr[j];
  }
  float* pb = part + kc * 16384 + wv * 64 + r8 * 8;
#pragma unroll
  for (int i = 0; i < 8; i++) {
    float4 s0 = make_float4(acc[i][0], acc[i][1], acc[i][2], acc[i][3]);
    float4 s1 = make_float4(acc[i][4], acc[i][5], acc[i][6], acc[i][7]);
    float* pp = pb + (b8 * 8 + i) * 256;
    *(float4*)pp = s0;
    *(float4*)(pp + 4) = s1;
  }
}

// Reduce partials: grid 256 = (kq 4) x (oq 64). hbuf[o] += sum_{kc in kq} part[kc][o]
__global__ __launch_bounds__(256) void k_r0red(const float* __restrict__ part,
    float* __restrict__ hbuf) {
  int blk = blockIdx.x;
  int oq = blk & 63, kq = blk >> 6;
  int o = oq * 256 + threadIdx.x;
  float s = 0.0f;
  const float* pp = part + kq * 64 * 16384 + o;
#pragma unroll 8
  for (int kc = 0; kc < 64; kc++) s += pp[kc * 16384];
  atomicAdd(&hbuf[o], s);
}

// grid 256 = (bb, pq): wt for 64 p's, partial res over those p's -> res4[pq][b][g]
__global__ __launch_bounds__(256) void k_wt_res(const float* __restrict__ hbuf,
    const float* __restrict__ r3_w, const float* __restrict__ r3_b,
    const float* __restrict__ yg, float* __restrict__ res4) {
  __shared__ float hs[256];
  __shared__ float wts[64];
  __shared__ float red[256];
  int blk = blockIdx.x;
  int bb = blk >> 2, pq = blk & 3;
  int t = threadIdx.x;
  float hv = hbuf[bb * 256 + t];
  hs[t] = hv > 0.0f ? hv : 0.01f * hv;
  __syncthreads();
  int pl = t >> 2, c = t & 3;
  int pp = pq * 64 + pl;
  const float4* wrow = (const float4*)(r3_w + pp * 256 + c * 64);
  const float4* h4 = (const float4*)(hs) + c * 16;
  float a = 0.0f;
#pragma unroll
  for (int j = 0; j < 16; j++) {
    float4 w4 = wrow[j], hh = h4[j];
    a += hh.x * w4.x + hh.y * w4.y + hh.z * w4.z + hh.w * w4.w;
  }
  a += __shfl_xor(a, 1);
  a += __shfl_xor(a, 2);
  if (c == 0) wts[pl] = fmaxf(a + r3_b[pp], 0.0f);
  __syncthreads();
  int g = t & 63, ch = t >> 6;
  float r = 0.0f;
  const float* ygp = yg + bb * 16384 + pq * 4096 + g;
#pragma unroll
  for (int pi = 0; pi < 16; pi++) {
    int pl2 = ch * 16 + pi;
    r += wts[pl2] * ygp[pl2 * 64];
  }
  red[t] = r;
  __syncthreads();
  if (t < 64)
    res4[pq * 4096 + bb * 64 + t] = red[t] + red[t + 64] + red[t + 128] + red[t + 192];
}

// z = elu([sum(res4), x2] @ l1_w^T + l1_b); out = z @ l3_w^T + l3_b
__global__ __launch_bounds__(128) void k_final(const float* __restrict__ res4,
    const float* __restrict__ x2, const float* __restrict__ l1_w,
    const float* __restrict__ l1_b, const float* __restrict__ l3_w,
    const float* __restrict__ l3_b, float* __restrict__ out) {
  __shared__ float zs[128];
  int bb = blockIdx.x, t = threadIdx.x;
  float acc = l1_b[t];
  const float* wrow = l1_w + t * 72;
  const float* rr = res4 + bb * 64;
#pragma unroll 8
  for (int j = 0; j < 64; j++) {
    float rv = rr[j] + rr[4096 + j] + rr[8192 + j] + rr[12288 + j];
    acc += rv * wrow[j];
  }
  const float* xr = x2 + bb * 8;
#pragma unroll
  for (int j = 0; j < 8; j++) acc += xr[j] * wrow[64 + j];
  zs[t] = acc > 0.0f ? acc : expm1f(acc);
  __syncthreads();
  if (t < 9) {
    float o = l3_b[t];
    const float* w3 = l3_w + t * 128;
    for (int j = 0; j < 128; j++) o += zs[j] * w3[j];
    out[bb * 9 + t] = o;
  }
}

extern "C" void kernel_launch(void* const* d_in, const int* in_sizes, int n_in,
                              void* d_out, int out_size, void* d_ws, size_t ws_size,
                              hipStream_t stream) {
  (void)in_sizes; (void)n_in; (void)out_size; (void)ws_size;
  const float* x1     = (const float*)d_in[0];
  const float* x2     = (const float*)d_in[1];
  const float* conv_w = (const float*)d_in[2];
  const float* conv_b = (const float*)d_in[3];
  const float* k1_w   = (const float*)d_in[4];
  const float* k1_b   = (const float*)d_in[5];
  const float* k2_w   = (const float*)d_in[6];
  const float* k3_w   = (const float*)d_in[7];
  const float* k4_w   = (const float*)d_in[8];
  const float* k5_w   = (const float*)d_in[9];
  const float* k5_b   = (const float*)d_in[10];
  const float* gc_w   = (const float*)d_in[11];
  const float* gc_b   = (const float*)d_in[12];
  const float* r0_w   = (const float*)d_in[13];
  const float* r1_w   = (const float*)d_in[14];
  const float* r1_b   = (const float*)d_in[15];
  const float* r2_w   = (const float*)d_in[16];
  const float* r3_w   = (const float*)d_in[17];
  const float* r3_b   = (const float*)d_in[18];
  const float* l1_w   = (const float*)d_in[19];
  const float* l1_b   = (const float*)d_in[20];
  const float* l3_w   = (const float*)d_in[21];
  const float* l3_b   = (const float*)d_in[22];
  const float* ef     = (const float*)d_in[23];
  const float* linc   = (const float*)d_in[24];
  const float* rinc   = (const float*)d_in[25];
  const float* cap    = (const float*)d_in[26];
  const int*   pidx   = (const int*)d_in[27];
  float* out = (float*)d_out;

  float* ws   = (float*)d_ws;
  float* xbuf = ws + X_OFF;
  float* t4   = ws + T4_OFF;
  float* t3   = ws + T3_OFF;
  float* kb   = ws + KB_OFF;
  float* yg   = ws + YG_OFF;
  float* hbuf = ws + HB_OFF;
  float* res4 = ws + RES_OFF;
  float* part = ws + X_OFF;   // aliases x/t4/t3/kb (dead after k_eagg)
  int* ib = (int*)(ws + INT_OFF);
  int* lidx = ib;
  int* ridx = ib + 4096;
  int* part_start = ib + 8192;
  int* part_edges = ib + 8704;

  hipLaunchKernelGGL(k_decode, dim3(3072), dim3(256), 0, stream, linc, rinc, lidx, ridx);
  hipLaunchKernelGGL(k_lists, dim3(1), dim3(1024), 0, stream, lidx, part_start, part_edges);
  hipLaunchKernelGGL(k_conv, dim3(512), dim3(256), 0, stream, x1, conv_w, conv_b, xbuf);
  hipLaunchKernelGGL(k_prep, dim3(1856), dim3(256), 0, stream,
                     xbuf, pidx, k3_w, k4_w, x2, k2_w, ef, k1_w, k1_b,
                     r1_w, r1_b, r2_w, cap, t4, t3, kb, hbuf);
  hipLaunchKernelGGL(k_eagg, dim3(256), dim3(256), 0, stream,
                     xbuf, kb, t3, t4, k5_w, k5_b, ridx, part_start, part_edges,
                     gc_w, gc_b, yg);
  hipLaunchKernelGGL(k_r0, dim3(256), dim3(256), 0, stream, yg, r0_w, part);
  hipLaunchKernelGGL(k_r0red, dim3(256), dim3(256), 0, stream, part, hbuf);
  hipLaunchKernelGGL(k_wt_res, dim3(256), dim3(256), 0, stream, hbuf, r3_w, r3_b, yg, res4);
  hipLaunchKernelGGL(k_final, dim3(64), dim3(128), 0, stream,
                     res4, x2, l1_w, l1_b, l3_w, l3_b, out);
}